// Round 3
// baseline (299.753 us; speedup 1.0000x reference)
//
#include <hip/hip_runtime.h>
#include <hip/hip_bf16.h>
#include <cstdint>

// ---------------------------------------------------------------------------
#define IMGSZ 224
#define OUTSZ 112
#define POOLSZ 56
#define OCN 128
#define BN_ 32
#define PIX1 (OUTSZ*OUTSZ)     // 12544
#define PIX2 (POOLSZ*POOLSZ)   // 3136
#define HP 58                  // padded pooled dim (56 + 2)
#define HSTRIDE (HP*HP*OCN)    // elems per n in h2p
#define PW 240                 // padded input row stride (x in [-3,236))
#define PH 233                 // padded input rows (y in [-3,230))
#define PPL (PH*PW)            // 55920 elems per padded plane
#define K1C 192                // conv1 K: 24 groups of 8 = (ic*7+ky)*8+kx layout

typedef float f32x4 __attribute__((ext_vector_type(4)));
typedef short bf16x8 __attribute__((ext_vector_type(8)));
struct alignas(4) u4a { unsigned x, y, z, w; };   // 4B-aligned 16B load

__device__ inline short f2bf(float v) {
    __hip_bfloat16 h = __float2bfloat16(v);
    return *(short*)&h;
}
__device__ inline unsigned pack2bf(float a, float b) {
    return (unsigned short)f2bf(a) | ((unsigned)(unsigned short)f2bf(b) << 16);
}
__device__ inline float bf2f(short s) {
    return __uint_as_float(((unsigned)(unsigned short)s) << 16);
}
__device__ inline bf16x8 ldb8(const short* p) {   // 16B load, 4B-aligned
    u4a t = *(const u4a*)p;
    union { u4a u; bf16x8 v; } c; c.u = t; return c.v;
}
__device__ inline void gload16(const short* g, short* l) {   // async global->LDS, 16B/lane
    __builtin_amdgcn_global_load_lds((const __attribute__((address_space(1))) void*)g,
                                     (__attribute__((address_space(3))) void*)l, 16, 0, 0);
}

// DPP 16-lane sum: quad_perm xor1, xor2, row_half_mirror (xor7), row_mirror
// (xor15). Pure VALU — replaces 4x ds_swizzle butterfly (DS pipe relief).
template<int CTRL>
__device__ inline float dppf(float v) {
    return __int_as_float(__builtin_amdgcn_update_dpp(0, __float_as_int(v), CTRL, 0xF, 0xF, true));
}
__device__ inline float rowsum16(float v) {
    v += dppf<0xB1>(v);    // quad_perm [1,0,3,2]  (xor 1)
    v += dppf<0x4E>(v);    // quad_perm [2,3,0,1]  (xor 2)
    v += dppf<0x141>(v);   // row_half_mirror      (xor 7)
    v += dppf<0x140>(v);   // row_mirror           (xor 15)
    return v;              // all 16 lanes of each row hold the 16-sum
}

// ---------------------------------------------------------------------------
// Fused setup: [0,49) map ; [49,145) wpack1 ; [145,721) wconv2 pack ;
// [721,785) stats zero ; [785,2609) h2p halo zero.
// wconv2 pack: w2b holds 18 K-step tiles (t = s*2 + ic_half), each the EXACT
// 16 KB LDS image: [oc 128][8 chunks of 16B], chunk slot = (ic6>>3) ^ (oc&7).
__global__ __launch_bounds__(256) void k_setup(const float* __restrict__ w1,
                                               short* __restrict__ w1b,
                                               const float* __restrict__ w2,
                                               short* __restrict__ w2b,
                                               int2* __restrict__ map,
                                               float* __restrict__ stats,
                                               unsigned* __restrict__ h2p) {
    int blk = blockIdx.x;
    int tid = threadIdx.x;
    if (blk < 49) {
        int p = blk * 256 + tid;
        int oy = p / OUTSZ, ox = p % OUTSZ;
        int e = min(min(oy, ox), min(111 - oy, 111 - ox));
        int s = e >> 3;
        int a = 16 * s, b = a + 16, c = 224 - b, d = 224 - a;
        int ao = a >> 1, bo = b >> 1, co = c >> 1, dd = d >> 1;
        int ti, li, bi, ri;
        if      (oy >= ao && oy < bo && ox >= ao && ox < co) { ti=a; li=a; bi=b; ri=c; }
        else if (oy >= bo && oy < dd && ox >= ao && ox < bo) { ti=b; li=a; bi=d; ri=b; }
        else if (oy >= co && oy < dd && ox >= bo && ox < dd) { ti=c; li=b; bi=d; ri=d; }
        else                                                 { ti=a; li=c; bi=c; ri=d; }
        float scale = (float)(2.0 - (double)s * 0.16666666666666666);
        int tip = (int)((float)(ti + 6) / scale) - 3;
        int lip = (int)((float)(li + 6) / scale) - 3;
        int bip = (int)((float)(bi + 6) / scale) + 3;
        int rip = (int)((float)(ri + 6) / scale) + 3;
        int fh = (bip - tip - 7) / 2 + 1;
        int fw = (rip - lip - 7) / 2 + 1;
        int to = ti >> 1, lo = li >> 1, bo2 = bi >> 1, ro = ri >> 1;
        int i = oy - to, j = ox - lo;
        int pp = (i * fh) / (bo2 - to);
        int qq = (j * fw) / (ro - lo);
        map[p] = make_int2(tip + 2 * pp, lip + 2 * qq);
    } else if (blk < 145) {
        int idx = (blk - 49) * 256 + tid;
        int oc = idx / K1C, k = idx % K1C;
        int g8 = k >> 3, e2 = k & 7;
        float v = 0.f;
        if (g8 < 21 && e2 < 7) {
            int ic = g8 / 7, ky = g8 - ic * 7;
            v = w1[((oc * 3 + ic) * 7 + ky) * 7 + e2];
        }
        w1b[idx] = f2bf(v);
    } else if (blk < 721) {
        int idx = (blk - 145) * 256 + tid;      // input element of w2 (OIHW flat)
        int oc = idx / 1152;
        int rem = idx - oc * 1152;
        int ic = rem / 9;
        int s  = rem - ic * 9;
        int t  = s * 2 + (ic >> 6);             // K-step
        int ic6 = ic & 63;
        int slot = (ic6 >> 3) ^ (oc & 7);       // XOR-swizzled 16B chunk slot
        w2b[t * 8192 + oc * 64 + slot * 8 + (ic6 & 7)] = f2bf(w2[idx]);
    } else if (blk < 785) {
        stats[(blk - 721) * 256 + tid] = 0.f;
    } else {
        int idx = blk - 785;                  // 0..1823
        int bx = idx % 57, n = idx / 57;
        int c2 = tid & 63, po = tid >> 6;
        int pp = bx * 4 + po;                 // 0..227
        int y, x;
        if      (pp < 58)  { y = 0;  x = pp; }
        else if (pp < 116) { y = 57; x = pp - 58; }
        else if (pp < 172) { y = pp - 116 + 1; x = 0; }
        else               { y = pp - 172 + 1; x = 57; }
        h2p[(size_t)n * (HSTRIDE / 2) + (y * HP + x) * 64 + c2] = 0u;
    }
}

// ---------------------------------------------------------------------------
// Zero-haloed padded bf16 input, TWO copies: padA[x] = img[x-3], padB[x] = img[x-2]
__global__ __launch_bounds__(256) void k_pad(const float* __restrict__ inp,
                                             short* __restrict__ padA,
                                             short* __restrict__ padB) {
    int x = threadIdx.x;
    if (x >= PW) return;
    int y = blockIdx.x;       // 0..232
    int pl = blockIdx.y;      // 0..95
    int iy = y - 3;
    bool yok = (unsigned)iy < 224u;
    const float* src = inp + (size_t)pl * 50176 + iy * 224;
    float vA = (yok && (unsigned)(x - 3) < 224u) ? src[x - 3] : 0.f;
    float vB = (yok && (unsigned)(x - 2) < 224u) ? src[x - 2] : 0.f;
    size_t o = (size_t)pl * PPL + y * PW + x;
    padA[o] = f2bf(vA);
    padB[o] = f2bf(vB);
}

// ---------------------------------------------------------------------------
// conv1 via MFMA. Wave = 64 oc x 32 px; block = 4 waves x 32 px = 128 px.
// A staged ONCE in compact 24 KB LDS (rows of 24 chunks, rotation swizzle
// slot=(c+row)%24 -> 2 lanes/bank = free). B = 12 up-front global 16B loads.
// Stats: DPP 16-lane rowsum (zero DS ops) + b64 sred + block combine.
// LDS 26.6 KB -> 6 blocks/CU (24 waves).
__global__ __launch_bounds__(256, 6) void k_conv1m(const short* __restrict__ padA,
                                                   const short* __restrict__ padB,
                                                   const short* __restrict__ w1b,
                                                   const int2* __restrict__ map,
                                                   short* __restrict__ out1b,
                                                   float* __restrict__ sum1x,
                                                   float* __restrict__ sq1x) {
    __shared__ short As[64 * 192];     // 24 KB: row r stride 192, slot=(c+r%24)%24
    __shared__ float2 sred[4][64];     // 2 KB
    int tid = threadIdx.x;
    int wave = tid >> 6, lane = tid & 63;
    int q = lane >> 4, l16 = lane & 15;
    int ochalf = blockIdx.x & 1;
    int pxblk = blockIdx.x >> 1;                      // 0..97
    int n = blockIdx.y;
    int px0 = pxblk * 128 + wave * 32 + l16;
    int px1 = px0 + 16;
    int2 m0 = map[px0];
    int2 m1 = map[px1];
    size_t bn = (size_t)n * 3 * PPL;
    const short* r0 = ((m0.y & 1) ? padB + (m0.y - 1) : padA + m0.y) + bn + m0.x * PW;
    const short* r1 = ((m1.y & 1) ? padB + (m1.y - 1) : padA + m1.y) + bn + m1.x * PW;

    // B loads first (longest latency; consumed in-order by MFMA loop)
    bf16x8 ld[12];
#pragma unroll
    for (int icc = 0; icc < 6; icc++) {
        int g8 = (icc == 5) ? 20 : (icc * 4 + q);
        int ic = (g8 >= 7) + (g8 >= 14);
        int ky = g8 - ic * 7;
        int off = ic * PPL + ky * PW;
        ld[icc * 2]     = ldb8(r0 + off);
        ld[icc * 2 + 1] = ldb8(r1 + off);
    }

    // Stage A: 64 rows x 24 chunks of 16B = 1536 chunks; 6 per thread.
    const short* wsl = w1b + ochalf * 64 * K1C;
#pragma unroll
    for (int i = 0; i < 6; i++) {
        int chunk = tid + i * 256;
        int r = chunk / 24, c = chunk - r * 24;
        int rm = r % 24;
        int sl = c + rm; if (sl >= 24) sl -= 24;
        u4a v = *(const u4a*)(wsl + r * K1C + c * 8);
        *(u4a*)(As + r * 192 + sl * 8) = v;
    }

    f32x4 acc[4][2];
#pragma unroll
    for (int t = 0; t < 4; t++) { acc[t][0] = (f32x4){0,0,0,0}; acc[t][1] = (f32x4){0,0,0,0}; }

    // per-lane A read bases: row = t*16 + l16
    int rowb[4], rowm[4];
#pragma unroll
    for (int t = 0; t < 4; t++) {
        int row = t * 16 + l16;
        rowb[t] = row * 192;
        rowm[t] = row % 24;
    }

    __syncthreads();

#pragma unroll
    for (int icc = 0; icc < 6; icc++) {
        bf16x8 bf0 = ld[icc * 2];
        bf16x8 bf1 = ld[icc * 2 + 1];
        int c = icc * 4 + q;
#pragma unroll
        for (int t = 0; t < 4; t++) {
            int sl = rowm[t] + c; if (sl >= 24) sl -= 24;
            bf16x8 af = *(const bf16x8*)(As + rowb[t] + sl * 8);
            acc[t][0] = __builtin_amdgcn_mfma_f32_16x16x32_bf16(af, bf0, acc[t][0], 0, 0, 0);
            acc[t][1] = __builtin_amdgcn_mfma_f32_16x16x32_bf16(af, bf1, acc[t][1], 0, 0, 0);
        }
    }

    // epilogue: C layout col(px)=l16, row(oc_local)=q*4+r ; store NHWC bf16
    short* ob = out1b + ((size_t)(n * PIX1) + px0) * OCN + ochalf * 64 + q * 4;
#pragma unroll
    for (int t = 0; t < 4; t++) {
#pragma unroll
        for (int g = 0; g < 2; g++) {
            f32x4 a = acc[t][g];
            uint2 u;
            u.x = pack2bf(a[0], a[1]);
            u.y = pack2bf(a[2], a[3]);
            *(uint2*)(ob + (size_t)g * 16 * OCN + t * 16) = u;
        }
    }

    // fused BN1 stats: DPP rowsum over 16 px-lanes (VALU only), b64 sred
#pragma unroll
    for (int t = 0; t < 4; t++) {
#pragma unroll
        for (int r = 0; r < 4; r++) {
            float a0 = acc[t][0][r], a1 = acc[t][1][r];
            float s = rowsum16(a0 + a1);
            float z = rowsum16(fmaf(a0, a0, a1 * a1));
            if (l16 == 0)
                sred[wave][t * 16 + q * 4 + r] = make_float2(s, z);
        }
    }
    __syncthreads();
    if (tid < 64) {
        float2 p0 = sred[0][tid], p1 = sred[1][tid], p2 = sred[2][tid], p3 = sred[3][tid];
        float s = p0.x + p1.x + p2.x + p3.x;
        float z = p0.y + p1.y + p2.y + p3.y;
        int oc = ochalf * 64 + tid;
        atomicAdd(&sum1x[n * OCN + oc], s);
        atomicAdd(&sq1x[n * OCN + oc], z);
    }
}

// ---------------------------------------------------------------------------
// Finalize BN params from per-n partial sums: 32x128 -> scale/shift.
__global__ void k_fin2(const float* __restrict__ sumx, const float* __restrict__ sqx,
                       const float* __restrict__ gamma, const float* __restrict__ beta,
                       float invN, float* __restrict__ scale, float* __restrict__ shift) {
    int c = threadIdx.x;
    if (c >= OCN) return;
    float s = 0.f, q = 0.f;
    for (int n = 0; n < BN_; n++) { s += sumx[n * OCN + c]; q += sqx[n * OCN + c]; }
    float m = s * invN;
    float v = q * invN - m * m;
    float sc = gamma[c] * rsqrtf(v + 1e-5f);
    scale[c] = sc;
    shift[c] = beta[c] - m * sc;
}

// ---------------------------------------------------------------------------
// BN1 affine + 3x3/2 maxpool + ReLU: NHWC bf16 (112x112) -> padded NHWC bf16 (58x58)
__global__ __launch_bounds__(256) void k_bnpool(const unsigned* __restrict__ out1b,
                                                const float* __restrict__ scale,
                                                const float* __restrict__ shift,
                                                unsigned* __restrict__ h2p) {
    int tid = threadIdx.x;
    int c2 = tid & 63, po = tid >> 6;
    int pp = blockIdx.x * 4 + po;
    int n = blockIdx.y;
    int py = pp / POOLSZ, px = pp % POOLSZ;
    const unsigned* base = out1b + (size_t)n * PIX1 * 64;
    float sc0 = scale[2 * c2],     sh0 = shift[2 * c2];
    float sc1 = scale[2 * c2 + 1], sh1 = shift[2 * c2 + 1];
    float m0 = -1e30f, m1 = -1e30f;
#pragma unroll
    for (int dy = 0; dy < 3; dy++) {
        int y = 2 * py - 1 + dy;
        if ((unsigned)y >= (unsigned)OUTSZ) continue;
#pragma unroll
        for (int dx = 0; dx < 3; dx++) {
            int x = 2 * px - 1 + dx;
            if ((unsigned)x >= (unsigned)OUTSZ) continue;
            unsigned u = base[(size_t)(y * OUTSZ + x) * 64 + c2];
            float v0 = __uint_as_float(u << 16);
            float v1 = __uint_as_float(u & 0xffff0000u);
            m0 = fmaxf(m0, fmaf(sc0, v0, sh0));
            m1 = fmaxf(m1, fmaf(sc1, v1, sh1));
        }
    }
    m0 = fmaxf(m0, 0.f); m1 = fmaxf(m1, 0.f);
    h2p[(size_t)n * (HSTRIDE / 2) + ((py + 1) * HP + (px + 1)) * 64 + c2] = pack2bf(m0, m1);
}

// ---------------------------------------------------------------------------
// conv2 v4: implicit GEMM, m97 structure, 64-px N-tiles (3136 = 49*64 exact).
// M=128 oc, BK=64 (18 K-steps). Grid 1568 = 8 XCD x 4n x 49 tiles -> 6
// blocks/CU (was grid-capped at 3.5). Wave = 32 oc x 64 px, acc[2][4].
// A (16 KB) + B (8 KB) single-buffer LDS via global_load_lds w=16; 2
// barriers/step. A source = w2b pre-packed swizzled tile image. B source =
// per-lane im2col gather, source pre-swizzled (m173). NHWC epilogue (full
// 256B lines/px). Stats: DPP rowsum + direct atomics (no sred).
__global__ __launch_bounds__(256, 6) void k_conv2g(const short* __restrict__ h2p,
                                                   const short* __restrict__ w2b,
                                                   short* __restrict__ out2b,
                                                   float* __restrict__ sum2x,
                                                   float* __restrict__ sq2x) {
    __shared__ short LDSb[12288];          // A: [0,8192) shorts; B: [8192,12288)
    int tid = threadIdx.x;
    int wave = tid >> 6, lane = tid & 63;
    int q = lane >> 4, l16 = lane & 15;
    int id = blockIdx.x;                   // 0..1567, XCD-major
    int xcd = id & 7, seq = id >> 3;       // seq 0..195
    int n = xcd + 8 * (seq / 49);
    int px0 = (seq % 49) * 64;
    const short* hb = h2p + (size_t)n * HSTRIDE;

    // B staging source offsets (2 chunks/thread, 512 chunks = 64 px x 8 slots)
    int bofs[2];
#pragma unroll
    for (int i = 0; i < 2; i++) {
        int ck = tid + i * 256;
        int px = ck >> 3, sl = ck & 7;
        int p = px0 + px;
        int y = p / POOLSZ, x = p - y * POOLSZ;
        bofs[i] = (y * HP + x) * 128 + ((sl ^ (px & 7)) * 8);
    }

    f32x4 acc[2][4];
#pragma unroll
    for (int t16 = 0; t16 < 2; t16++)
#pragma unroll
        for (int g = 0; g < 4; g++) acc[t16][g] = (f32x4){0, 0, 0, 0};

    const short* Az = LDSb;
    const short* Bz = LDSb + 8192;
    int arow0 = (wave * 32 + l16) * 64;
    int arow1 = arow0 + 16 * 64;

    for (int t = 0; t < 18; t++) {
        __syncthreads();                   // previous compute done in all waves
        const short* wt = w2b + t * 8192;
#pragma unroll
        for (int i = 0; i < 4; i++)
            gload16(wt + (tid + i * 256) * 8, &LDSb[(tid + i * 256) * 8]);
        int s = t >> 1, ich = t & 1;
        int dy = s / 3, dx = s - dy * 3;
        int doff = (dy * HP + dx) * 128 + ich * 64;
#pragma unroll
        for (int i = 0; i < 2; i++)
            gload16(hb + bofs[i] + doff, &LDSb[8192 + (tid + i * 256) * 8]);
        asm volatile("s_waitcnt vmcnt(0)" ::: "memory");
        __syncthreads();
#pragma unroll
        for (int icc2 = 0; icc2 < 2; icc2++) {
            int so = ((icc2 * 4 + q) ^ (l16 & 7)) * 8;
            bf16x8 af0 = *(const bf16x8*)(Az + arow0 + so);
            bf16x8 af1 = *(const bf16x8*)(Az + arow1 + so);
            bf16x8 bf[4];
#pragma unroll
            for (int g = 0; g < 4; g++)
                bf[g] = *(const bf16x8*)(Bz + (g * 16 + l16) * 64 + so);
#pragma unroll
            for (int g = 0; g < 4; g++) {
                acc[0][g] = __builtin_amdgcn_mfma_f32_16x16x32_bf16(af0, bf[g], acc[0][g], 0, 0, 0);
                acc[1][g] = __builtin_amdgcn_mfma_f32_16x16x32_bf16(af1, bf[g], acc[1][g], 0, 0, 0);
            }
        }
    }

    // ---- epilogue: C col(px)=l16, row(oc)=q*4+r ; store NHWC bf16 ----
    short* ob = out2b + ((size_t)n * PIX2 + px0) * OCN + wave * 32 + q * 4;
#pragma unroll
    for (int t16 = 0; t16 < 2; t16++) {
#pragma unroll
        for (int g = 0; g < 4; g++) {
            f32x4 a = acc[t16][g];
            uint2 u;
            u.x = pack2bf(a[0], a[1]);
            u.y = pack2bf(a[2], a[3]);
            *(uint2*)(ob + (size_t)(g * 16 + l16) * OCN + t16 * 16) = u;
        }
    }

    // ---- fused BN2 stats: DPP rowsum; waves own distinct oc -> atomics ----
#pragma unroll
    for (int t16 = 0; t16 < 2; t16++) {
#pragma unroll
        for (int r = 0; r < 4; r++) {
            float sv = 0.f, zv = 0.f;
#pragma unroll
            for (int g = 0; g < 4; g++) {
                float v = acc[t16][g][r];
                sv += v;
                zv = fmaf(v, v, zv);
            }
            sv = rowsum16(sv);
            zv = rowsum16(zv);
            if (l16 == 0) {
                int oc = wave * 32 + t16 * 16 + q * 4 + r;
                atomicAdd(&sum2x[n * OCN + oc], sv);
                atomicAdd(&sq2x[n * OCN + oc], zv);
            }
        }
    }
}

// ---------------------------------------------------------------------------
// BN2 affine + ReLU: NHWC bf16 out2b -> NCHW fp32 d_out.
// Thread = 4 px x 8 c (x4 c-groups): register-local 4x8 transpose, no LDS.
__global__ __launch_bounds__(256) void k_bnrelu(const short* __restrict__ in2,
                                                float* __restrict__ y,
                                                const float* __restrict__ scale,
                                                const float* __restrict__ shift) {
    int tid = threadIdx.x;
    int w = tid >> 6, l = tid & 63;
    int pxg = blockIdx.x * 256 + w * 64 + (l & 15) * 4;  // wave spans 64 px (never crosses n)
    int n = pxg / PIX2;
    int px = pxg - n * PIX2;
    const short* src = in2 + (size_t)pxg * OCN + (l >> 4) * 8;
    float* dst = y + (size_t)n * (OCN * PIX2) + px;
#pragma unroll
    for (int jc = 0; jc < 4; jc++) {
        int c0 = (l >> 4) * 8 + jc * 32;
        bf16x8 v0 = ldb8(src + jc * 32);
        bf16x8 v1 = ldb8(src + OCN + jc * 32);
        bf16x8 v2 = ldb8(src + 2 * OCN + jc * 32);
        bf16x8 v3 = ldb8(src + 3 * OCN + jc * 32);
#pragma unroll
        for (int j = 0; j < 8; j++) {
            float sc = scale[c0 + j], sh = shift[c0 + j];
            float4 o;
            o.x = fmaxf(fmaf(sc, bf2f(v0[j]), sh), 0.f);
            o.y = fmaxf(fmaf(sc, bf2f(v1[j]), sh), 0.f);
            o.z = fmaxf(fmaf(sc, bf2f(v2[j]), sh), 0.f);
            o.w = fmaxf(fmaf(sc, bf2f(v3[j]), sh), 0.f);
            *(float4*)(dst + (size_t)(c0 + j) * PIX2) = o;
        }
    }
}

// ---------------------------------------------------------------------------
extern "C" void kernel_launch(void* const* d_in, const int* in_sizes, int n_in,
                              void* d_out, int out_size, void* d_ws, size_t ws_size,
                              hipStream_t stream) {
    const float* inp = (const float*)d_in[0];
    const float* w1  = (const float*)d_in[1];
    const float* g1  = (const float*)d_in[2];
    const float* b1  = (const float*)d_in[3];
    const float* w2  = (const float*)d_in[4];
    const float* g2  = (const float*)d_in[5];
    const float* b2  = (const float*)d_in[6];
    float* out = (float*)d_out;

    char* ws = (char*)d_ws;
    int2*  map   = (int2*)ws;                         // 100,352 B
    float* stats = (float*)(ws + 102400);             // 65,536 B zeroed in k_setup
    short* w2b   = (short*)(ws + 176128);             // 294,912 B -> 471,040
    short* w1b   = (short*)(ws + 471040);             // 49,152 B  -> 520,192
    short* padA  = (short*)(ws + 520192);             // 10,736,640 B -> 11,256,832
    short* padB  = (short*)(ws + 11256832ULL);        // 10,736,640 B -> 21,993,472
    short* h2p   = (short*)(ws + 21993472ULL);        // 27,557,888 B -> 49,551,360
    short* out1b = (short*)(ws + 49551360ULL);        // 102,760,448 B -> 152,311,808
    short* out2b = (short*)(ws + 152311808ULL);       // 25,690,112 B -> 178,001,920 (NHWC)

    float* sum1x = stats;                // 32*128
    float* sq1x  = stats + 4096;
    float* sum2x = stats + 8192;
    float* sq2x  = stats + 12288;
    float* SC1 = stats + 16384, *SH1 = stats + 16512;
    float* SC2 = stats + 16640, *SH2 = stats + 16768;

    k_setup <<<dim3(2609), 256, 0, stream>>>(w1, w1b, w2, w2b, map, stats, (unsigned*)h2p);
    k_pad   <<<dim3(PH, 96), 256, 0, stream>>>(inp, padA, padB);
    k_conv1m<<<dim3(196, BN_), 256, 0, stream>>>(padA, padB, w1b, map, out1b, sum1x, sq1x);
    k_fin2  <<<1, 128, 0, stream>>>(sum1x, sq1x, g1, b1, 1.f / (BN_ * PIX1), SC1, SH1);
    k_bnpool<<<dim3(PIX2 / 4, BN_), 256, 0, stream>>>((const unsigned*)out1b, SC1, SH1, (unsigned*)h2p);
    k_conv2g<<<dim3(1568), 256, 0, stream>>>(h2p, w2b, out2b, sum2x, sq2x);
    k_fin2  <<<1, 128, 0, stream>>>(sum2x, sq2x, g2, b2, 1.f / (BN_ * PIX2), SC2, SH2);
    k_bnrelu<<<dim3(392), 256, 0, stream>>>(out2b, out, SC2, SH2);
}

// Round 4
// 293.711 us; speedup vs baseline: 1.0206x; 1.0206x over previous
//
#include <hip/hip_runtime.h>
#include <hip/hip_bf16.h>
#include <cstdint>

// ---------------------------------------------------------------------------
#define IMGSZ 224
#define OUTSZ 112
#define POOLSZ 56
#define OCN 128
#define BN_ 32
#define PIX1 (OUTSZ*OUTSZ)     // 12544
#define PIX2 (POOLSZ*POOLSZ)   // 3136
#define HP 58                  // padded pooled dim (56 + 2)
#define HSTRIDE (HP*HP*OCN)    // elems per n in h2p
#define PW 240                 // padded input row stride (x in [-3,236))
#define PH 233                 // padded input rows (y in [-3,230))
#define PPL (PH*PW)            // 55920 elems per padded plane
#define K1C 192                // conv1 K: 24 groups of 8 = (ic*7+ky)*8+kx layout

typedef float f32x4 __attribute__((ext_vector_type(4)));
typedef short bf16x8 __attribute__((ext_vector_type(8)));
struct alignas(4) u4a { unsigned x, y, z, w; };   // 4B-aligned 16B load

__device__ inline short f2bf(float v) {
    __hip_bfloat16 h = __float2bfloat16(v);
    return *(short*)&h;
}
__device__ inline unsigned pack2bf(float a, float b) {
    return (unsigned short)f2bf(a) | ((unsigned)(unsigned short)f2bf(b) << 16);
}
__device__ inline float bf2f(short s) {
    return __uint_as_float(((unsigned)(unsigned short)s) << 16);
}
__device__ inline bf16x8 ldb8(const short* p) {   // 16B load, 4B-aligned
    u4a t = *(const u4a*)p;
    union { u4a u; bf16x8 v; } c; c.u = t; return c.v;
}
__device__ inline void gload16(const short* g, short* l) {   // async global->LDS, 16B/lane
    __builtin_amdgcn_global_load_lds((const __attribute__((address_space(1))) void*)g,
                                     (__attribute__((address_space(3))) void*)l, 16, 0, 0);
}

// DPP 16-lane sum: quad_perm xor1, xor2, row_half_mirror (xor7), row_mirror
// (xor15). Pure VALU — replaces 4x ds_swizzle butterfly (DS pipe relief).
template<int CTRL>
__device__ inline float dppf(float v) {
    return __int_as_float(__builtin_amdgcn_update_dpp(0, __float_as_int(v), CTRL, 0xF, 0xF, true));
}
__device__ inline float rowsum16(float v) {
    v += dppf<0xB1>(v);    // quad_perm [1,0,3,2]  (xor 1)
    v += dppf<0x4E>(v);    // quad_perm [2,3,0,1]  (xor 2)
    v += dppf<0x141>(v);   // row_half_mirror      (xor 7)
    v += dppf<0x140>(v);   // row_mirror           (xor 15)
    return v;              // all 16 lanes of each row hold the 16-sum
}

// ---------------------------------------------------------------------------
// Fused setup: [0,49) map ; [49,145) wpack1 ; [145,721) wconv2 pack ;
// [721,785) stats zero ; [785,2609) h2p halo zero.
// OC-PERMUTED packs: A-tile storage row holds the weights of the oc that the
// MFMA lane layout makes register-contiguous, so conv epilogues emit full
// 16B stores (fixes partial-line HBM write amplification seen in r2).
// conv1: row t*16+q*4+r  holds oc q*16+t*4+r  (within each 64-oc half).
// conv2: row t16*16+q*4+r holds oc q*8+t16*4+r (within each 32-oc wave slice).
__global__ __launch_bounds__(256) void k_setup(const float* __restrict__ w1,
                                               short* __restrict__ w1b,
                                               const float* __restrict__ w2,
                                               short* __restrict__ w2b,
                                               int2* __restrict__ map,
                                               float* __restrict__ stats,
                                               unsigned* __restrict__ h2p) {
    int blk = blockIdx.x;
    int tid = threadIdx.x;
    if (blk < 49) {
        int p = blk * 256 + tid;
        int oy = p / OUTSZ, ox = p % OUTSZ;
        int e = min(min(oy, ox), min(111 - oy, 111 - ox));
        int s = e >> 3;
        int a = 16 * s, b = a + 16, c = 224 - b, d = 224 - a;
        int ao = a >> 1, bo = b >> 1, co = c >> 1, dd = d >> 1;
        int ti, li, bi, ri;
        if      (oy >= ao && oy < bo && ox >= ao && ox < co) { ti=a; li=a; bi=b; ri=c; }
        else if (oy >= bo && oy < dd && ox >= ao && ox < bo) { ti=b; li=a; bi=d; ri=b; }
        else if (oy >= co && oy < dd && ox >= bo && ox < dd) { ti=c; li=b; bi=d; ri=d; }
        else                                                 { ti=a; li=c; bi=c; ri=d; }
        float scale = (float)(2.0 - (double)s * 0.16666666666666666);
        int tip = (int)((float)(ti + 6) / scale) - 3;
        int lip = (int)((float)(li + 6) / scale) - 3;
        int bip = (int)((float)(bi + 6) / scale) + 3;
        int rip = (int)((float)(ri + 6) / scale) + 3;
        int fh = (bip - tip - 7) / 2 + 1;
        int fw = (rip - lip - 7) / 2 + 1;
        int to = ti >> 1, lo = li >> 1, bo2 = bi >> 1, ro = ri >> 1;
        int i = oy - to, j = ox - lo;
        int pp = (i * fh) / (bo2 - to);
        int qq = (j * fw) / (ro - lo);
        map[p] = make_int2(tip + 2 * pp, lip + 2 * qq);
    } else if (blk < 145) {
        int idx = (blk - 49) * 256 + tid;       // storage position (row-major)
        int rowg = idx / K1C, k = idx % K1C;
        int rowl = rowg & 63;
        int t = rowl >> 4, q = (rowl >> 2) & 3, r = rowl & 3;
        int ocg = (rowg & 64) + q * 16 + t * 4 + r;   // permuted source oc
        int g8 = k >> 3, e2 = k & 7;
        float v = 0.f;
        if (g8 < 21 && e2 < 7) {
            int ic = g8 / 7, ky = g8 - ic * 7;
            v = w1[((ocg * 3 + ic) * 7 + ky) * 7 + e2];
        }
        w1b[idx] = f2bf(v);
    } else if (blk < 721) {
        int idx = (blk - 145) * 256 + tid;      // input element of w2 (OIHW flat)
        int oc = idx / 1152;
        int rem = idx - oc * 1152;
        int ic = rem / 9;
        int s  = rem - ic * 9;
        int t  = s * 2 + (ic >> 6);             // K-step
        int ic6 = ic & 63;
        // destination storage row for this oc (permuted):
        int o5 = oc & 31;
        int q = o5 >> 3, kk = o5 & 7;
        int t16 = kk >> 2, r = kk & 3;
        int arow = (oc & ~31) + t16 * 16 + q * 4 + r;
        int slot = (ic6 >> 3) ^ (arow & 7);     // XOR-swizzled 16B chunk slot
        w2b[t * 8192 + arow * 64 + slot * 8 + (ic6 & 7)] = f2bf(w2[idx]);
    } else if (blk < 785) {
        stats[(blk - 721) * 256 + tid] = 0.f;
    } else {
        int idx = blk - 785;                  // 0..1823
        int bx = idx % 57, n = idx / 57;
        int c2 = tid & 63, po = tid >> 6;
        int pp = bx * 4 + po;                 // 0..227
        int y, x;
        if      (pp < 58)  { y = 0;  x = pp; }
        else if (pp < 116) { y = 57; x = pp - 58; }
        else if (pp < 172) { y = pp - 116 + 1; x = 0; }
        else               { y = pp - 172 + 1; x = 57; }
        h2p[(size_t)n * (HSTRIDE / 2) + (y * HP + x) * 64 + c2] = 0u;
    }
}

// ---------------------------------------------------------------------------
// Zero-haloed padded bf16 input, TWO copies: padA[x] = img[x-3], padB[x] = img[x-2]
__global__ __launch_bounds__(256) void k_pad(const float* __restrict__ inp,
                                             short* __restrict__ padA,
                                             short* __restrict__ padB) {
    int x = threadIdx.x;
    if (x >= PW) return;
    int y = blockIdx.x;       // 0..232
    int pl = blockIdx.y;      // 0..95
    int iy = y - 3;
    bool yok = (unsigned)iy < 224u;
    const float* src = inp + (size_t)pl * 50176 + iy * 224;
    float vA = (yok && (unsigned)(x - 3) < 224u) ? src[x - 3] : 0.f;
    float vB = (yok && (unsigned)(x - 2) < 224u) ? src[x - 2] : 0.f;
    size_t o = (size_t)pl * PPL + y * PW + x;
    padA[o] = f2bf(vA);
    padB[o] = f2bf(vB);
}

// ---------------------------------------------------------------------------
// conv1 via MFMA. Wave = 64 oc x 32 px; block = 4 waves x 32 px = 128 px.
// A staged ONCE in compact 24 KB LDS (rows of 24 chunks, swizzle (c+3r)%24 ->
// bank residues cycle across rows). B = 12 up-front global 16B loads.
// oc-permuted A rows -> epilogue = 2x16B contiguous stores per px (full-line
// coverage, no partial-line RMW at HBM). Stats: DPP rowsum, zero DS ops.
// LDS 26.6 KB -> 6 blocks/CU.
__global__ __launch_bounds__(256, 6) void k_conv1m(const short* __restrict__ padA,
                                                   const short* __restrict__ padB,
                                                   const short* __restrict__ w1b,
                                                   const int2* __restrict__ map,
                                                   short* __restrict__ out1b,
                                                   float* __restrict__ sum1x,
                                                   float* __restrict__ sq1x) {
    __shared__ short As[64 * 192];     // 24 KB: row r stride 192, slot=(c+3r)%24
    __shared__ float2 sred[4][64];     // 2 KB
    int tid = threadIdx.x;
    int wave = tid >> 6, lane = tid & 63;
    int q = lane >> 4, l16 = lane & 15;
    int ochalf = blockIdx.x & 1;
    int pxblk = blockIdx.x >> 1;                      // 0..97
    int n = blockIdx.y;
    int px0 = pxblk * 128 + wave * 32 + l16;
    int px1 = px0 + 16;
    int2 m0 = map[px0];
    int2 m1 = map[px1];
    size_t bn = (size_t)n * 3 * PPL;
    const short* r0 = ((m0.y & 1) ? padB + (m0.y - 1) : padA + m0.y) + bn + m0.x * PW;
    const short* r1 = ((m1.y & 1) ? padB + (m1.y - 1) : padA + m1.y) + bn + m1.x * PW;

    // B loads first (longest latency; consumed in-order by MFMA loop)
    bf16x8 ld[12];
#pragma unroll
    for (int icc = 0; icc < 6; icc++) {
        int g8 = (icc == 5) ? 20 : (icc * 4 + q);
        int ic = (g8 >= 7) + (g8 >= 14);
        int ky = g8 - ic * 7;
        int off = ic * PPL + ky * PW;
        ld[icc * 2]     = ldb8(r0 + off);
        ld[icc * 2 + 1] = ldb8(r1 + off);
    }

    // Stage A: 64 rows x 24 chunks of 16B = 1536 chunks; 6 per thread.
    const short* wsl = w1b + ochalf * 64 * K1C;
#pragma unroll
    for (int i = 0; i < 6; i++) {
        int chunk = tid + i * 256;
        int r = chunk / 24, c = chunk - r * 24;
        int sl = c + (3 * r) % 24; if (sl >= 24) sl -= 24;
        u4a v = *(const u4a*)(wsl + r * K1C + c * 8);
        *(u4a*)(As + r * 192 + sl * 8) = v;
    }

    f32x4 acc[4][2];
#pragma unroll
    for (int t = 0; t < 4; t++) { acc[t][0] = (f32x4){0,0,0,0}; acc[t][1] = (f32x4){0,0,0,0}; }

    // per-lane A read bases: row = t*16 + l16
    int rowb[4], rowm[4];
#pragma unroll
    for (int t = 0; t < 4; t++) {
        int row = t * 16 + l16;
        rowb[t] = row * 192;
        rowm[t] = (3 * row) % 24;
    }

    __syncthreads();

#pragma unroll
    for (int icc = 0; icc < 6; icc++) {
        bf16x8 bf0 = ld[icc * 2];
        bf16x8 bf1 = ld[icc * 2 + 1];
        int c = icc * 4 + q;
#pragma unroll
        for (int t = 0; t < 4; t++) {
            int sl = rowm[t] + c; if (sl >= 24) sl -= 24;
            bf16x8 af = *(const bf16x8*)(As + rowb[t] + sl * 8);
            acc[t][0] = __builtin_amdgcn_mfma_f32_16x16x32_bf16(af, bf0, acc[t][0], 0, 0, 0);
            acc[t][1] = __builtin_amdgcn_mfma_f32_16x16x32_bf16(af, bf1, acc[t][1], 0, 0, 0);
        }
    }

    // epilogue: lane q holds oc ochalf*64 + q*16 .. +15 per px (permuted pack)
    // -> 2 contiguous 16B stores per px; NHWC bf16.
    short* ob = out1b + ((size_t)(n * PIX1) + px0) * OCN + ochalf * 64 + q * 16;
#pragma unroll
    for (int g = 0; g < 2; g++) {
        u4a u0, u1;
        u0.x = pack2bf(acc[0][g][0], acc[0][g][1]);
        u0.y = pack2bf(acc[0][g][2], acc[0][g][3]);
        u0.z = pack2bf(acc[1][g][0], acc[1][g][1]);
        u0.w = pack2bf(acc[1][g][2], acc[1][g][3]);
        u1.x = pack2bf(acc[2][g][0], acc[2][g][1]);
        u1.y = pack2bf(acc[2][g][2], acc[2][g][3]);
        u1.z = pack2bf(acc[3][g][0], acc[3][g][1]);
        u1.w = pack2bf(acc[3][g][2], acc[3][g][3]);
        *(u4a*)(ob + (size_t)g * 16 * OCN)     = u0;
        *(u4a*)(ob + (size_t)g * 16 * OCN + 8) = u1;
    }

    // fused BN1 stats: DPP rowsum over 16 px-lanes (VALU only)
#pragma unroll
    for (int t = 0; t < 4; t++) {
#pragma unroll
        for (int r = 0; r < 4; r++) {
            float a0 = acc[t][0][r], a1 = acc[t][1][r];
            float s = rowsum16(a0 + a1);
            float z = rowsum16(fmaf(a0, a0, a1 * a1));
            if (l16 == 0)
                sred[wave][q * 16 + t * 4 + r] = make_float2(s, z);
        }
    }
    __syncthreads();
    if (tid < 64) {
        float2 p0 = sred[0][tid], p1 = sred[1][tid], p2 = sred[2][tid], p3 = sred[3][tid];
        float s = p0.x + p1.x + p2.x + p3.x;
        float z = p0.y + p1.y + p2.y + p3.y;
        int oc = ochalf * 64 + tid;
        atomicAdd(&sum1x[n * OCN + oc], s);
        atomicAdd(&sq1x[n * OCN + oc], z);
    }
}

// ---------------------------------------------------------------------------
// Finalize BN params from per-n partial sums: 32x128 -> scale/shift.
__global__ void k_fin2(const float* __restrict__ sumx, const float* __restrict__ sqx,
                       const float* __restrict__ gamma, const float* __restrict__ beta,
                       float invN, float* __restrict__ scale, float* __restrict__ shift) {
    int c = threadIdx.x;
    if (c >= OCN) return;
    float s = 0.f, q = 0.f;
    for (int n = 0; n < BN_; n++) { s += sumx[n * OCN + c]; q += sqx[n * OCN + c]; }
    float m = s * invN;
    float v = q * invN - m * m;
    float sc = gamma[c] * rsqrtf(v + 1e-5f);
    scale[c] = sc;
    shift[c] = beta[c] - m * sc;
}

// ---------------------------------------------------------------------------
// BN1 affine + 3x3/2 maxpool + ReLU: NHWC bf16 (112x112) -> padded NHWC bf16 (58x58)
__global__ __launch_bounds__(256) void k_bnpool(const unsigned* __restrict__ out1b,
                                                const float* __restrict__ scale,
                                                const float* __restrict__ shift,
                                                unsigned* __restrict__ h2p) {
    int tid = threadIdx.x;
    int c2 = tid & 63, po = tid >> 6;
    int pp = blockIdx.x * 4 + po;
    int n = blockIdx.y;
    int py = pp / POOLSZ, px = pp % POOLSZ;
    const unsigned* base = out1b + (size_t)n * PIX1 * 64;
    float sc0 = scale[2 * c2],     sh0 = shift[2 * c2];
    float sc1 = scale[2 * c2 + 1], sh1 = shift[2 * c2 + 1];
    float m0 = -1e30f, m1 = -1e30f;
#pragma unroll
    for (int dy = 0; dy < 3; dy++) {
        int y = 2 * py - 1 + dy;
        if ((unsigned)y >= (unsigned)OUTSZ) continue;
#pragma unroll
        for (int dx = 0; dx < 3; dx++) {
            int x = 2 * px - 1 + dx;
            if ((unsigned)x >= (unsigned)OUTSZ) continue;
            unsigned u = base[(size_t)(y * OUTSZ + x) * 64 + c2];
            float v0 = __uint_as_float(u << 16);
            float v1 = __uint_as_float(u & 0xffff0000u);
            m0 = fmaxf(m0, fmaf(sc0, v0, sh0));
            m1 = fmaxf(m1, fmaf(sc1, v1, sh1));
        }
    }
    m0 = fmaxf(m0, 0.f); m1 = fmaxf(m1, 0.f);
    h2p[(size_t)n * (HSTRIDE / 2) + ((py + 1) * HP + (px + 1)) * 64 + c2] = pack2bf(m0, m1);
}

// ---------------------------------------------------------------------------
// conv2 v5: implicit GEMM, m97 structure, 112-px N-tiles (r1-proven; 28 MFMA
// per barrier pair). M=128 oc, BK=64 (18 K-steps). Grid 896, XCD-major.
// A (16 KB) + B (14 KB) single-buffer LDS via global_load_lds w=16.
// A source = w2b pre-packed swizzled + OC-PERMUTED tile image -> epilogue is
// ONE 16B contiguous store per px per lane (full-line NHWC writes).
// Stats: DPP rowsum + direct atomics.
__global__ __launch_bounds__(256, 4) void k_conv2g(const short* __restrict__ h2p,
                                                   const short* __restrict__ w2b,
                                                   short* __restrict__ out2b,
                                                   float* __restrict__ sum2x,
                                                   float* __restrict__ sq2x) {
    __shared__ short LDSb[15360];          // A: [0,8192) shorts; B: [8192,15360)
    int tid = threadIdx.x;
    int wave = tid >> 6, lane = tid & 63;
    int q = lane >> 4, l16 = lane & 15;
    int id = blockIdx.x;                   // 0..895, XCD-major
    int xcd = id & 7, seq = id >> 3;       // seq 0..111
    int n = xcd + 8 * (seq / 28);
    int rb = seq % 28;
    int y0 = rb * 2;                       // output rows y0, y0+1
    const short* hb = h2p + (size_t)n * HSTRIDE;

    // B staging source offsets (896 chunks = 112 px x 8 slots)
    int bofs[4];
#pragma unroll
    for (int i = 0; i < 4; i++) {
        int ck = tid + i * 256;
        if (ck > 895) ck = 895;            // i==3, tid>=128: lanes inactive
        int px = ck >> 3, sl = ck & 7;
        int r = px >= 56;
        int xc = px - (r ? 56 : 0);
        bofs[i] = ((y0 + r) * HP + xc) * 128 + ((sl ^ (px & 7)) * 8);
    }

    f32x4 acc[2][7];
#pragma unroll
    for (int t16 = 0; t16 < 2; t16++)
#pragma unroll
        for (int g = 0; g < 7; g++) acc[t16][g] = (f32x4){0, 0, 0, 0};

    const short* Az = LDSb;
    const short* Bz = LDSb + 8192;
    int arow0 = (wave * 32 + l16) * 64;
    int arow1 = arow0 + 16 * 64;

    for (int t = 0; t < 18; t++) {
        __syncthreads();                   // previous compute done in all waves
        const short* wt = w2b + t * 8192;
#pragma unroll
        for (int i = 0; i < 4; i++)
            gload16(wt + (tid + i * 256) * 8, &LDSb[(tid + i * 256) * 8]);
        int s = t >> 1, ich = t & 1;
        int dy = s / 3, dx = s - dy * 3;
        int doff = (dy * HP + dx) * 128 + ich * 64;
#pragma unroll
        for (int i = 0; i < 3; i++)
            gload16(hb + bofs[i] + doff, &LDSb[8192 + (tid + i * 256) * 8]);
        if (tid < 128)
            gload16(hb + bofs[3] + doff, &LDSb[8192 + (tid + 768) * 8]);
        asm volatile("s_waitcnt vmcnt(0)" ::: "memory");
        __syncthreads();
#pragma unroll
        for (int icc2 = 0; icc2 < 2; icc2++) {
            int so = ((icc2 * 4 + q) ^ (l16 & 7)) * 8;
            bf16x8 af0 = *(const bf16x8*)(Az + arow0 + so);
            bf16x8 af1 = *(const bf16x8*)(Az + arow1 + so);
            bf16x8 bf[7];
#pragma unroll
            for (int g = 0; g < 7; g++)
                bf[g] = *(const bf16x8*)(Bz + (g * 16 + l16) * 64 + so);
#pragma unroll
            for (int g = 0; g < 7; g++) {
                acc[0][g] = __builtin_amdgcn_mfma_f32_16x16x32_bf16(af0, bf[g], acc[0][g], 0, 0, 0);
                acc[1][g] = __builtin_amdgcn_mfma_f32_16x16x32_bf16(af1, bf[g], acc[1][g], 0, 0, 0);
            }
        }
    }

    // ---- epilogue: lane q holds oc wave*32 + q*8 .. +7 per px -> one 16B
    //      contiguous store per px; NHWC bf16. ----
    short* ob = out2b + ((size_t)n * PIX2 + y0 * 56) * OCN + wave * 32 + q * 8;
#pragma unroll
    for (int g = 0; g < 7; g++) {
        u4a u;
        u.x = pack2bf(acc[0][g][0], acc[0][g][1]);
        u.y = pack2bf(acc[0][g][2], acc[0][g][3]);
        u.z = pack2bf(acc[1][g][0], acc[1][g][1]);
        u.w = pack2bf(acc[1][g][2], acc[1][g][3]);
        *(u4a*)(ob + (size_t)(g * 16 + l16) * OCN) = u;
    }

    // ---- fused BN2 stats: DPP rowsum; waves own distinct oc -> atomics ----
#pragma unroll
    for (int t16 = 0; t16 < 2; t16++) {
#pragma unroll
        for (int r = 0; r < 4; r++) {
            float sv = 0.f, zv = 0.f;
#pragma unroll
            for (int g = 0; g < 7; g++) {
                float v = acc[t16][g][r];
                sv += v;
                zv = fmaf(v, v, zv);
            }
            sv = rowsum16(sv);
            zv = rowsum16(zv);
            if (l16 == 0) {
                int oc = wave * 32 + q * 8 + t16 * 4 + r;   // permuted mapping
                atomicAdd(&sum2x[n * OCN + oc], sv);
                atomicAdd(&sq2x[n * OCN + oc], zv);
            }
        }
    }
}

// ---------------------------------------------------------------------------
// BN2 affine + ReLU: NHWC bf16 out2b -> NCHW fp32 d_out.
// Thread = 4 px x 8 c (x4 c-groups): register-local 4x8 transpose, no LDS.
__global__ __launch_bounds__(256) void k_bnrelu(const short* __restrict__ in2,
                                                float* __restrict__ y,
                                                const float* __restrict__ scale,
                                                const float* __restrict__ shift) {
    int tid = threadIdx.x;
    int w = tid >> 6, l = tid & 63;
    int pxg = blockIdx.x * 256 + w * 64 + (l & 15) * 4;  // wave spans 64 px (never crosses n)
    int n = pxg / PIX2;
    int px = pxg - n * PIX2;
    const short* src = in2 + (size_t)pxg * OCN + (l >> 4) * 8;
    float* dst = y + (size_t)n * (OCN * PIX2) + px;
#pragma unroll
    for (int jc = 0; jc < 4; jc++) {
        int c0 = (l >> 4) * 8 + jc * 32;
        bf16x8 v0 = ldb8(src + jc * 32);
        bf16x8 v1 = ldb8(src + OCN + jc * 32);
        bf16x8 v2 = ldb8(src + 2 * OCN + jc * 32);
        bf16x8 v3 = ldb8(src + 3 * OCN + jc * 32);
#pragma unroll
        for (int j = 0; j < 8; j++) {
            float sc = scale[c0 + j], sh = shift[c0 + j];
            float4 o;
            o.x = fmaxf(fmaf(sc, bf2f(v0[j]), sh), 0.f);
            o.y = fmaxf(fmaf(sc, bf2f(v1[j]), sh), 0.f);
            o.z = fmaxf(fmaf(sc, bf2f(v2[j]), sh), 0.f);
            o.w = fmaxf(fmaf(sc, bf2f(v3[j]), sh), 0.f);
            *(float4*)(dst + (size_t)(c0 + j) * PIX2) = o;
        }
    }
}

// ---------------------------------------------------------------------------
extern "C" void kernel_launch(void* const* d_in, const int* in_sizes, int n_in,
                              void* d_out, int out_size, void* d_ws, size_t ws_size,
                              hipStream_t stream) {
    const float* inp = (const float*)d_in[0];
    const float* w1  = (const float*)d_in[1];
    const float* g1  = (const float*)d_in[2];
    const float* b1  = (const float*)d_in[3];
    const float* w2  = (const float*)d_in[4];
    const float* g2  = (const float*)d_in[5];
    const float* b2  = (const float*)d_in[6];
    float* out = (float*)d_out;

    char* ws = (char*)d_ws;
    int2*  map   = (int2*)ws;                         // 100,352 B
    float* stats = (float*)(ws + 102400);             // 65,536 B zeroed in k_setup
    short* w2b   = (short*)(ws + 176128);             // 294,912 B -> 471,040
    short* w1b   = (short*)(ws + 471040);             // 49,152 B  -> 520,192
    short* padA  = (short*)(ws + 520192);             // 10,736,640 B -> 11,256,832
    short* padB  = (short*)(ws + 11256832ULL);        // 10,736,640 B -> 21,993,472
    short* h2p   = (short*)(ws + 21993472ULL);        // 27,557,888 B -> 49,551,360
    short* out1b = (short*)(ws + 49551360ULL);        // 102,760,448 B -> 152,311,808
    short* out2b = (short*)(ws + 152311808ULL);       // 25,690,112 B -> 178,001,920 (NHWC)

    float* sum1x = stats;                // 32*128
    float* sq1x  = stats + 4096;
    float* sum2x = stats + 8192;
    float* sq2x  = stats + 12288;
    float* SC1 = stats + 16384, *SH1 = stats + 16512;
    float* SC2 = stats + 16640, *SH2 = stats + 16768;

    k_setup <<<dim3(2609), 256, 0, stream>>>(w1, w1b, w2, w2b, map, stats, (unsigned*)h2p);
    k_pad   <<<dim3(PH, 96), 256, 0, stream>>>(inp, padA, padB);
    k_conv1m<<<dim3(196, BN_), 256, 0, stream>>>(padA, padB, w1b, map, out1b, sum1x, sq1x);
    k_fin2  <<<1, 128, 0, stream>>>(sum1x, sq1x, g1, b1, 1.f / (BN_ * PIX1), SC1, SH1);
    k_bnpool<<<dim3(PIX2 / 4, BN_), 256, 0, stream>>>((const unsigned*)out1b, SC1, SH1, (unsigned*)h2p);
    k_conv2g<<<dim3(896), 256, 0, stream>>>(h2p, w2b, out2b, sum2x, sq2x);
    k_fin2  <<<1, 128, 0, stream>>>(sum2x, sq2x, g2, b2, 1.f / (BN_ * PIX2), SC2, SH2);
    k_bnrelu<<<dim3(392), 256, 0, stream>>>(out2b, out, SC2, SH2);
}

// Round 5
// 250.497 us; speedup vs baseline: 1.1966x; 1.1725x over previous
//
#include <hip/hip_runtime.h>
#include <hip/hip_bf16.h>
#include <cstdint>

// ---------------------------------------------------------------------------
#define IMGSZ 224
#define OUTSZ 112
#define POOLSZ 56
#define OCN 128
#define BN_ 32
#define PIX1 (OUTSZ*OUTSZ)     // 12544
#define PIX2 (POOLSZ*POOLSZ)   // 3136
#define HP 58                  // padded pooled dim (56 + 2)
#define HSTRIDE (HP*HP*OCN)    // elems per n in h2p
#define PW 240                 // padded input row stride (x in [-3,236))
#define PH 233                 // padded input rows (y in [-3,230))
#define PPL (PH*PW)            // 55920 elems per padded plane
#define K1C 192                // conv1 K: 24 groups of 8 = (ic*7+ky)*8+kx layout

typedef float f32x4 __attribute__((ext_vector_type(4)));
typedef short bf16x8 __attribute__((ext_vector_type(8)));
struct alignas(4) u4a { unsigned x, y, z, w; };   // 4B-aligned 16B load

__device__ inline short f2bf(float v) {
    __hip_bfloat16 h = __float2bfloat16(v);
    return *(short*)&h;
}
__device__ inline unsigned pack2bf(float a, float b) {
    return (unsigned short)f2bf(a) | ((unsigned)(unsigned short)f2bf(b) << 16);
}
__device__ inline float bf2f(short s) {
    return __uint_as_float(((unsigned)(unsigned short)s) << 16);
}
__device__ inline bf16x8 ldb8(const short* p) {   // 16B load, 4B-aligned
    u4a t = *(const u4a*)p;
    union { u4a u; bf16x8 v; } c; c.u = t; return c.v;
}
__device__ inline void gload16(const short* g, short* l) {   // async global->LDS, 16B/lane
    __builtin_amdgcn_global_load_lds((const __attribute__((address_space(1))) void*)g,
                                     (__attribute__((address_space(3))) void*)l, 16, 0, 0);
}

// DPP 16-lane sum: quad_perm xor1, xor2, row_half_mirror, row_mirror.
// Pure VALU — replaces the 4-step ds_swizzle butterfly (DS pipe relief).
// Numerically identical to the shfl version (validated r2/r3 pass).
template<int CTRL>
__device__ inline float dppf(float v) {
    return __int_as_float(__builtin_amdgcn_update_dpp(0, __float_as_int(v), CTRL, 0xF, 0xF, true));
}
__device__ inline float rowsum16(float v) {
    v += dppf<0xB1>(v);    // quad_perm [1,0,3,2]  (xor 1)
    v += dppf<0x4E>(v);    // quad_perm [2,3,0,1]  (xor 2)
    v += dppf<0x141>(v);   // row_half_mirror      (8-group sum)
    v += dppf<0x140>(v);   // row_mirror           (16-group sum)
    return v;              // all 16 lanes of each row hold the 16-sum
}

// ---------------------------------------------------------------------------
// Fused setup: [0,49) map ; [49,145) wpack1 ; [145,721) wconv2 pack ;
// [721,785) stats zero ; [785,2609) h2p halo zero.
// wconv2 pack: w2b holds 18 K-step tiles (t = s*2 + ic_half), each the EXACT
// 16 KB LDS image: [oc 128][8 chunks of 16B], chunk slot = (ic6>>3) ^ (oc&7).
__global__ __launch_bounds__(256) void k_setup(const float* __restrict__ w1,
                                               short* __restrict__ w1b,
                                               const float* __restrict__ w2,
                                               short* __restrict__ w2b,
                                               int2* __restrict__ map,
                                               float* __restrict__ stats,
                                               unsigned* __restrict__ h2p) {
    int blk = blockIdx.x;
    int tid = threadIdx.x;
    if (blk < 49) {
        int p = blk * 256 + tid;
        int oy = p / OUTSZ, ox = p % OUTSZ;
        int e = min(min(oy, ox), min(111 - oy, 111 - ox));
        int s = e >> 3;
        int a = 16 * s, b = a + 16, c = 224 - b, d = 224 - a;
        int ao = a >> 1, bo = b >> 1, co = c >> 1, dd = d >> 1;
        int ti, li, bi, ri;
        if      (oy >= ao && oy < bo && ox >= ao && ox < co) { ti=a; li=a; bi=b; ri=c; }
        else if (oy >= bo && oy < dd && ox >= ao && ox < bo) { ti=b; li=a; bi=d; ri=b; }
        else if (oy >= co && oy < dd && ox >= bo && ox < dd) { ti=c; li=b; bi=d; ri=d; }
        else                                                 { ti=a; li=c; bi=c; ri=d; }
        float scale = (float)(2.0 - (double)s * 0.16666666666666666);
        int tip = (int)((float)(ti + 6) / scale) - 3;
        int lip = (int)((float)(li + 6) / scale) - 3;
        int bip = (int)((float)(bi + 6) / scale) + 3;
        int rip = (int)((float)(ri + 6) / scale) + 3;
        int fh = (bip - tip - 7) / 2 + 1;
        int fw = (rip - lip - 7) / 2 + 1;
        int to = ti >> 1, lo = li >> 1, bo2 = bi >> 1, ro = ri >> 1;
        int i = oy - to, j = ox - lo;
        int pp = (i * fh) / (bo2 - to);
        int qq = (j * fw) / (ro - lo);
        map[p] = make_int2(tip + 2 * pp, lip + 2 * qq);
    } else if (blk < 145) {
        int idx = (blk - 49) * 256 + tid;
        int oc = idx / K1C, k = idx % K1C;
        int g8 = k >> 3, e2 = k & 7;
        float v = 0.f;
        if (g8 < 21 && e2 < 7) {
            int ic = g8 / 7, ky = g8 - ic * 7;
            v = w1[((oc * 3 + ic) * 7 + ky) * 7 + e2];
        }
        w1b[idx] = f2bf(v);
    } else if (blk < 721) {
        int idx = (blk - 145) * 256 + tid;      // input element of w2 (OIHW flat)
        int oc = idx / 1152;
        int rem = idx - oc * 1152;
        int ic = rem / 9;
        int s  = rem - ic * 9;
        int t  = s * 2 + (ic >> 6);             // K-step
        int ic6 = ic & 63;
        int slot = (ic6 >> 3) ^ (oc & 7);       // XOR-swizzled 16B chunk slot
        w2b[t * 8192 + oc * 64 + slot * 8 + (ic6 & 7)] = f2bf(w2[idx]);
    } else if (blk < 785) {
        stats[(blk - 721) * 256 + tid] = 0.f;
    } else {
        int idx = blk - 785;                  // 0..1823
        int bx = idx % 57, n = idx / 57;
        int c2 = tid & 63, po = tid >> 6;
        int pp = bx * 4 + po;                 // 0..227
        int y, x;
        if      (pp < 58)  { y = 0;  x = pp; }
        else if (pp < 116) { y = 57; x = pp - 58; }
        else if (pp < 172) { y = pp - 116 + 1; x = 0; }
        else               { y = pp - 172 + 1; x = 57; }
        h2p[(size_t)n * (HSTRIDE / 2) + (y * HP + x) * 64 + c2] = 0u;
    }
}

// ---------------------------------------------------------------------------
// Zero-haloed padded bf16 input, TWO copies: padA[x] = img[x-3], padB[x] = img[x-2]
__global__ __launch_bounds__(256) void k_pad(const float* __restrict__ inp,
                                             short* __restrict__ padA,
                                             short* __restrict__ padB) {
    int x = threadIdx.x;
    if (x >= PW) return;
    int y = blockIdx.x;       // 0..232
    int pl = blockIdx.y;      // 0..95
    int iy = y - 3;
    bool yok = (unsigned)iy < 224u;
    const float* src = inp + (size_t)pl * 50176 + iy * 224;
    float vA = (yok && (unsigned)(x - 3) < 224u) ? src[x - 3] : 0.f;
    float vB = (yok && (unsigned)(x - 2) < 224u) ? src[x - 2] : 0.f;
    size_t o = (size_t)pl * PPL + y * PW + x;
    padA[o] = f2bf(vA);
    padB[o] = f2bf(vB);
}

// ---------------------------------------------------------------------------
// conv1 via MFMA. Wave = 64 oc x 32 px; block = 4 waves x 32 px = 128 px,
// all on the same 64-oc A-slice. A staged ONCE in LDS (24 KB -> padded 32 KB,
// 16B-chunk XOR swizzle); B = 12 up-front global 16B loads per wave.
// r4: XCD n-chunked 1D grid (each XCD owns 4 complete images -> pad-gather
// L2-resident per XCD); stats reduce via DPP (zero DS ops). Everything else
// identical to the proven r1 version (4 blk/CU, clean W=103MB).
__global__ __launch_bounds__(256, 4) void k_conv1m(const short* __restrict__ padA,
                                                   const short* __restrict__ padB,
                                                   const short* __restrict__ w1b,
                                                   const int2* __restrict__ map,
                                                   short* __restrict__ out1b,
                                                   float* __restrict__ sum1x,
                                                   float* __restrict__ sq1x) {
    __shared__ short As[64 * 256];     // 32 KB: row r, 16B-chunk c at pos c^(r&15)
    __shared__ float sred[4][64][2];   // 2 KB
    int tid = threadIdx.x;
    int wave = tid >> 6, lane = tid & 63;
    int q = lane >> 4, l16 = lane & 15;
    // XCD-chunked id remap: 6272 = 8 XCD x 784; 784 = 4 images x 196 blocks.
    int id = blockIdx.x;
    int swz = (id & 7) * 784 + (id >> 3);
    int n = swz / 196;
    int x196 = swz - n * 196;
    int ochalf = x196 & 1;
    int pxblk = x196 >> 1;                            // 0..97
    int px0 = pxblk * 128 + wave * 32 + l16;
    int px1 = px0 + 16;
    int2 m0 = map[px0];
    int2 m1 = map[px1];
    size_t bn = (size_t)n * 3 * PPL;
    const short* r0 = ((m0.y & 1) ? padB + (m0.y - 1) : padA + m0.y) + bn + m0.x * PW;
    const short* r1 = ((m1.y & 1) ? padB + (m1.y - 1) : padA + m1.y) + bn + m1.x * PW;

    // Stage A: 64 rows x 24 chunks of 16B = 1536 chunks; 6 per thread.
    const short* wsl = w1b + ochalf * 64 * K1C;
#pragma unroll
    for (int i = 0; i < 6; i++) {
        int chunk = tid + i * 256;
        int r = chunk / 24, c = chunk - r * 24;
        u4a v = *(const u4a*)(wsl + r * K1C + c * 8);
        *(u4a*)(As + r * 256 + ((c ^ (r & 15)) * 8)) = v;
    }

    // B loads (up-front, in-order consumption)
    bf16x8 ld[12];
#pragma unroll
    for (int icc = 0; icc < 6; icc++) {
        int g8 = (icc == 5) ? 20 : (icc * 4 + q);
        int ic = (g8 >= 7) + (g8 >= 14);
        int ky = g8 - ic * 7;
        int off = ic * PPL + ky * PW;
        ld[icc * 2]     = ldb8(r0 + off);
        ld[icc * 2 + 1] = ldb8(r1 + off);
    }

    f32x4 acc[4][2];
#pragma unroll
    for (int t = 0; t < 4; t++) { acc[t][0] = (f32x4){0,0,0,0}; acc[t][1] = (f32x4){0,0,0,0}; }

    __syncthreads();

    const short* Abase = As + l16 * 256;   // + t*16*256 + swizzled chunk
#pragma unroll
    for (int icc = 0; icc < 6; icc++) {
        bf16x8 bf0 = ld[icc * 2];
        bf16x8 bf1 = ld[icc * 2 + 1];
        int pos = ((icc * 4 + q) ^ l16) * 8;
#pragma unroll
        for (int t = 0; t < 4; t++) {
            bf16x8 af = *(const bf16x8*)(Abase + t * 16 * 256 + pos);
            acc[t][0] = __builtin_amdgcn_mfma_f32_16x16x32_bf16(af, bf0, acc[t][0], 0, 0, 0);
            acc[t][1] = __builtin_amdgcn_mfma_f32_16x16x32_bf16(af, bf1, acc[t][1], 0, 0, 0);
        }
    }

    // epilogue: C layout col(px)=l16, row(oc_local)=q*4+r ; store NHWC bf16
    short* ob = out1b + ((size_t)(n * PIX1) + px0) * OCN + ochalf * 64 + q * 4;
#pragma unroll
    for (int t = 0; t < 4; t++) {
#pragma unroll
        for (int g = 0; g < 2; g++) {
            f32x4 a = acc[t][g];
            uint2 u;
            u.x = pack2bf(a[0], a[1]);
            u.y = pack2bf(a[2], a[3]);
            *(uint2*)(ob + (size_t)g * 16 * OCN + t * 16) = u;
        }
    }

    // fused BN1 stats: DPP 16-lane rowsum (VALU only) -> LDS -> block pass
#pragma unroll
    for (int t = 0; t < 4; t++) {
#pragma unroll
        for (int r = 0; r < 4; r++) {
            float a0 = acc[t][0][r], a1 = acc[t][1][r];
            float s = rowsum16(a0 + a1);
            float z = rowsum16(fmaf(a0, a0, a1 * a1));
            if (l16 == 0) {
                int ocl = t * 16 + q * 4 + r;     // 0..63
                sred[wave][ocl][0] = s;
                sred[wave][ocl][1] = z;
            }
        }
    }
    __syncthreads();
    if (tid < 64) {
        float s = sred[0][tid][0] + sred[1][tid][0] + sred[2][tid][0] + sred[3][tid][0];
        float z = sred[0][tid][1] + sred[1][tid][1] + sred[2][tid][1] + sred[3][tid][1];
        int oc = ochalf * 64 + tid;
        atomicAdd(&sum1x[n * OCN + oc], s);
        atomicAdd(&sq1x[n * OCN + oc], z);
    }
}

// ---------------------------------------------------------------------------
// Finalize BN params from per-n partial sums: 32x128 -> scale/shift.
__global__ void k_fin2(const float* __restrict__ sumx, const float* __restrict__ sqx,
                       const float* __restrict__ gamma, const float* __restrict__ beta,
                       float invN, float* __restrict__ scale, float* __restrict__ shift) {
    int c = threadIdx.x;
    if (c >= OCN) return;
    float s = 0.f, q = 0.f;
    for (int n = 0; n < BN_; n++) { s += sumx[n * OCN + c]; q += sqx[n * OCN + c]; }
    float m = s * invN;
    float v = q * invN - m * m;
    float sc = gamma[c] * rsqrtf(v + 1e-5f);
    scale[c] = sc;
    shift[c] = beta[c] - m * sc;
}

// ---------------------------------------------------------------------------
// BN1 affine + 3x3/2 maxpool + ReLU: NHWC bf16 (112x112) -> padded NHWC bf16 (58x58)
__global__ __launch_bounds__(256) void k_bnpool(const unsigned* __restrict__ out1b,
                                                const float* __restrict__ scale,
                                                const float* __restrict__ shift,
                                                unsigned* __restrict__ h2p) {
    int tid = threadIdx.x;
    int c2 = tid & 63, po = tid >> 6;
    int pp = blockIdx.x * 4 + po;
    int n = blockIdx.y;
    int py = pp / POOLSZ, px = pp % POOLSZ;
    const unsigned* base = out1b + (size_t)n * PIX1 * 64;
    float sc0 = scale[2 * c2],     sh0 = shift[2 * c2];
    float sc1 = scale[2 * c2 + 1], sh1 = shift[2 * c2 + 1];
    float m0 = -1e30f, m1 = -1e30f;
#pragma unroll
    for (int dy = 0; dy < 3; dy++) {
        int y = 2 * py - 1 + dy;
        if ((unsigned)y >= (unsigned)OUTSZ) continue;
#pragma unroll
        for (int dx = 0; dx < 3; dx++) {
            int x = 2 * px - 1 + dx;
            if ((unsigned)x >= (unsigned)OUTSZ) continue;
            unsigned u = base[(size_t)(y * OUTSZ + x) * 64 + c2];
            float v0 = __uint_as_float(u << 16);
            float v1 = __uint_as_float(u & 0xffff0000u);
            m0 = fmaxf(m0, fmaf(sc0, v0, sh0));
            m1 = fmaxf(m1, fmaf(sc1, v1, sh1));
        }
    }
    m0 = fmaxf(m0, 0.f); m1 = fmaxf(m1, 0.f);
    h2p[(size_t)n * (HSTRIDE / 2) + ((py + 1) * HP + (px + 1)) * 64 + c2] = pack2bf(m0, m1);
}

// ---------------------------------------------------------------------------
// conv2 v3 (r1-proven): implicit GEMM, m97 structure. M=128 oc, N-tile=112 px
// (2 rows), BK=64 (18 K-steps). 4 waves, each 32 oc x 112 px. A (16 KB) +
// B (14 KB) single-buffer LDS via global_load_lds w=16 each K-step; 2
// barriers/step; 4 blocks/CU hide the drain. A source = w2b pre-packed
// swizzled tile image (linear copy). B source = per-lane im2col gather with
// pre-swizzled source. NHWC epilogue. r4 delta: stats via DPP (no ds_swizzle).
__global__ __launch_bounds__(256, 4) void k_conv2g(const short* __restrict__ h2p,
                                                   const short* __restrict__ w2b,
                                                   short* __restrict__ out2b,
                                                   float* __restrict__ sum2x,
                                                   float* __restrict__ sq2x) {
    __shared__ short LDSb[15360];          // A: [0,8192) shorts; B: [8192,15360)
    int tid = threadIdx.x;
    int wave = tid >> 6, lane = tid & 63;
    int q = lane >> 4, l16 = lane & 15;
    int id = blockIdx.x;                   // 0..895, XCD-major
    int xcd = id & 7, seq = id >> 3;       // seq 0..111
    int n = xcd + 8 * (seq / 28);
    int rb = seq % 28;
    int y0 = rb * 2;                       // output rows y0, y0+1
    const short* hb = h2p + (size_t)n * HSTRIDE;

    // B staging source offsets (elems, step-delta excluded)
    int bofs[4];
#pragma unroll
    for (int i = 0; i < 4; i++) {
        int ck = tid + i * 256;
        if (ck > 895) ck = 895;            // i==3, tid>=128: lanes inactive
        int px = ck >> 3, sl = ck & 7;
        int r = px >= 56;
        int xc = px - (r ? 56 : 0);
        bofs[i] = ((y0 + r) * 58 + xc) * 128 + ((sl ^ (px & 7)) * 8);
    }

    f32x4 acc[2][7];
#pragma unroll
    for (int t16 = 0; t16 < 2; t16++)
#pragma unroll
        for (int g = 0; g < 7; g++) acc[t16][g] = (f32x4){0, 0, 0, 0};

    const short* Az = LDSb;
    const short* Bz = LDSb + 8192;
    int arow0 = (wave * 32 + l16) * 64;
    int arow1 = arow0 + 16 * 64;

    for (int t = 0; t < 18; t++) {
        __syncthreads();                   // previous compute done in all waves
        // ---- stage A (4x16B/thread, linear) + B (3.5x16B/thread, pre-swz src)
        const short* wt = w2b + t * 8192;
#pragma unroll
        for (int i = 0; i < 4; i++)
            gload16(wt + (tid + i * 256) * 8, &LDSb[(tid + i * 256) * 8]);
        int s = t >> 1, ich = t & 1;
        int dy = s / 3, dx = s - dy * 3;
        int doff = (dy * 58 + dx) * 128 + ich * 64;
#pragma unroll
        for (int i = 0; i < 3; i++)
            gload16(hb + bofs[i] + doff, &LDSb[8192 + (tid + i * 256) * 8]);
        if (tid < 128)
            gload16(hb + bofs[3] + doff, &LDSb[8192 + (tid + 768) * 8]);
        asm volatile("s_waitcnt vmcnt(0)" ::: "memory");
        __syncthreads();
        // ---- compute: 2 k-sub x (2 A-frag reads + 7 B-frag reads + 14 MFMA)
#pragma unroll
        for (int icc2 = 0; icc2 < 2; icc2++) {
            int so = ((icc2 * 4 + q) ^ (l16 & 7)) * 8;
            bf16x8 af0 = *(const bf16x8*)(Az + arow0 + so);
            bf16x8 af1 = *(const bf16x8*)(Az + arow1 + so);
            bf16x8 bf[7];
#pragma unroll
            for (int g = 0; g < 7; g++)
                bf[g] = *(const bf16x8*)(Bz + (g * 16 + l16) * 64 + so);
#pragma unroll
            for (int g = 0; g < 7; g++) {
                acc[0][g] = __builtin_amdgcn_mfma_f32_16x16x32_bf16(af0, bf[g], acc[0][g], 0, 0, 0);
                acc[1][g] = __builtin_amdgcn_mfma_f32_16x16x32_bf16(af1, bf[g], acc[1][g], 0, 0, 0);
            }
        }
    }

    // ---- epilogue: C col(px)=l16, row(oc)=q*4+r ; store NHWC bf16 ----
    short* ob = out2b + ((size_t)n * PIX2 + y0 * 56) * OCN + wave * 32 + q * 4;
#pragma unroll
    for (int t16 = 0; t16 < 2; t16++) {
#pragma unroll
        for (int g = 0; g < 7; g++) {
            f32x4 a = acc[t16][g];
            uint2 u;
            u.x = pack2bf(a[0], a[1]);
            u.y = pack2bf(a[2], a[3]);
            *(uint2*)(ob + (size_t)(g * 16 + l16) * OCN + t16 * 16) = u;
        }
    }

    // ---- fused BN2 stats: DPP rowsum; waves own distinct oc -> atomics ----
#pragma unroll
    for (int t16 = 0; t16 < 2; t16++) {
#pragma unroll
        for (int r = 0; r < 4; r++) {
            float sv = 0.f, zv = 0.f;
#pragma unroll
            for (int g = 0; g < 7; g++) {
                float v = acc[t16][g][r];
                sv += v;
                zv = fmaf(v, v, zv);
            }
            sv = rowsum16(sv);
            zv = rowsum16(zv);
            if (l16 == 0) {
                int oc = wave * 32 + t16 * 16 + q * 4 + r;
                atomicAdd(&sum2x[n * OCN + oc], sv);
                atomicAdd(&sq2x[n * OCN + oc], zv);
            }
        }
    }
}

// ---------------------------------------------------------------------------
// BN2 affine + ReLU: NHWC bf16 out2b -> NCHW fp32 d_out.
// Thread = 4 px x 8 c (x4 c-groups): register-local 4x8 transpose, no LDS.
__global__ __launch_bounds__(256) void k_bnrelu(const short* __restrict__ in2,
                                                float* __restrict__ y,
                                                const float* __restrict__ scale,
                                                const float* __restrict__ shift) {
    int tid = threadIdx.x;
    int w = tid >> 6, l = tid & 63;
    int pxg = blockIdx.x * 256 + w * 64 + (l & 15) * 4;  // wave spans 64 px (never crosses n)
    int n = pxg / PIX2;
    int px = pxg - n * PIX2;
    const short* src = in2 + (size_t)pxg * OCN + (l >> 4) * 8;
    float* dst = y + (size_t)n * (OCN * PIX2) + px;
#pragma unroll
    for (int jc = 0; jc < 4; jc++) {
        int c0 = (l >> 4) * 8 + jc * 32;
        bf16x8 v0 = ldb8(src + jc * 32);
        bf16x8 v1 = ldb8(src + OCN + jc * 32);
        bf16x8 v2 = ldb8(src + 2 * OCN + jc * 32);
        bf16x8 v3 = ldb8(src + 3 * OCN + jc * 32);
#pragma unroll
        for (int j = 0; j < 8; j++) {
            float sc = scale[c0 + j], sh = shift[c0 + j];
            float4 o;
            o.x = fmaxf(fmaf(sc, bf2f(v0[j]), sh), 0.f);
            o.y = fmaxf(fmaf(sc, bf2f(v1[j]), sh), 0.f);
            o.z = fmaxf(fmaf(sc, bf2f(v2[j]), sh), 0.f);
            o.w = fmaxf(fmaf(sc, bf2f(v3[j]), sh), 0.f);
            *(float4*)(dst + (size_t)(c0 + j) * PIX2) = o;
        }
    }
}

// ---------------------------------------------------------------------------
extern "C" void kernel_launch(void* const* d_in, const int* in_sizes, int n_in,
                              void* d_out, int out_size, void* d_ws, size_t ws_size,
                              hipStream_t stream) {
    const float* inp = (const float*)d_in[0];
    const float* w1  = (const float*)d_in[1];
    const float* g1  = (const float*)d_in[2];
    const float* b1  = (const float*)d_in[3];
    const float* w2  = (const float*)d_in[4];
    const float* g2  = (const float*)d_in[5];
    const float* b2  = (const float*)d_in[6];
    float* out = (float*)d_out;

    char* ws = (char*)d_ws;
    int2*  map   = (int2*)ws;                         // 100,352 B
    float* stats = (float*)(ws + 102400);             // 65,536 B zeroed in k_setup
    short* w2b   = (short*)(ws + 176128);             // 294,912 B -> 471,040
    short* w1b   = (short*)(ws + 471040);             // 49,152 B  -> 520,192
    short* padA  = (short*)(ws + 520192);             // 10,736,640 B -> 11,256,832
    short* padB  = (short*)(ws + 11256832ULL);        // 10,736,640 B -> 21,993,472
    short* h2p   = (short*)(ws + 21993472ULL);        // 27,557,888 B -> 49,551,360
    short* out1b = (short*)(ws + 49551360ULL);        // 102,760,448 B -> 152,311,808
    short* out2b = (short*)(ws + 152311808ULL);       // 25,690,112 B -> 178,001,920 (NHWC)

    float* sum1x = stats;                // 32*128
    float* sq1x  = stats + 4096;
    float* sum2x = stats + 8192;
    float* sq2x  = stats + 12288;
    float* SC1 = stats + 16384, *SH1 = stats + 16512;
    float* SC2 = stats + 16640, *SH2 = stats + 16768;

    k_setup <<<dim3(2609), 256, 0, stream>>>(w1, w1b, w2, w2b, map, stats, (unsigned*)h2p);
    k_pad   <<<dim3(PH, 96), 256, 0, stream>>>(inp, padA, padB);
    k_conv1m<<<dim3(6272), 256, 0, stream>>>(padA, padB, w1b, map, out1b, sum1x, sq1x);
    k_fin2  <<<1, 128, 0, stream>>>(sum1x, sq1x, g1, b1, 1.f / (BN_ * PIX1), SC1, SH1);
    k_bnpool<<<dim3(PIX2 / 4, BN_), 256, 0, stream>>>((const unsigned*)out1b, SC1, SH1, (unsigned*)h2p);
    k_conv2g<<<dim3(896), 256, 0, stream>>>(h2p, w2b, out2b, sum2x, sq2x);
    k_fin2  <<<1, 128, 0, stream>>>(sum2x, sq2x, g2, b2, 1.f / (BN_ * PIX2), SC2, SH2);
    k_bnrelu<<<dim3(392), 256, 0, stream>>>(out2b, out, SC2, SH2);
}

// Round 6
// 234.238 us; speedup vs baseline: 1.2797x; 1.0694x over previous
//
#include <hip/hip_runtime.h>
#include <hip/hip_bf16.h>
#include <cstdint>

// ---------------------------------------------------------------------------
#define IMGSZ 224
#define OUTSZ 112
#define POOLSZ 56
#define OCN 128
#define BN_ 32
#define PIX1 (OUTSZ*OUTSZ)     // 12544
#define PIX2 (POOLSZ*POOLSZ)   // 3136
#define HP 58                  // padded pooled dim (56 + 2)
#define HSTRIDE (HP*HP*OCN)    // elems per n in h2p
#define PW 240                 // padded input row stride (x in [-3,236))
#define PH 233                 // padded input rows (y in [-3,230))
#define PPL (PH*PW)            // 55920 elems per padded plane
#define K1C 192                // conv1 K: 24 groups of 8 = (ic*7+ky)*8+kx layout

typedef float f32x4 __attribute__((ext_vector_type(4)));
typedef short bf16x8 __attribute__((ext_vector_type(8)));
struct alignas(4) u4a { unsigned x, y, z, w; };   // 4B-aligned 16B load

__device__ inline short f2bf(float v) {
    __hip_bfloat16 h = __float2bfloat16(v);
    return *(short*)&h;
}
__device__ inline unsigned pack2bf(float a, float b) {
    return (unsigned short)f2bf(a) | ((unsigned)(unsigned short)f2bf(b) << 16);
}
__device__ inline float bf2f(short s) {
    return __uint_as_float(((unsigned)(unsigned short)s) << 16);
}
__device__ inline bf16x8 ldb8(const short* p) {   // 16B load, 4B-aligned
    u4a t = *(const u4a*)p;
    union { u4a u; bf16x8 v; } c; c.u = t; return c.v;
}
__device__ inline void gload16(const short* g, short* l) {   // async global->LDS, 16B/lane
    __builtin_amdgcn_global_load_lds((const __attribute__((address_space(1))) void*)g,
                                     (__attribute__((address_space(3))) void*)l, 16, 0, 0);
}

// DPP 16-lane sum: quad_perm xor1, xor2, row_half_mirror, row_mirror.
// Pure VALU — replaces the 4-step ds_swizzle butterfly (DS pipe relief).
template<int CTRL>
__device__ inline float dppf(float v) {
    return __int_as_float(__builtin_amdgcn_update_dpp(0, __float_as_int(v), CTRL, 0xF, 0xF, true));
}
__device__ inline float rowsum16(float v) {
    v += dppf<0xB1>(v);    // quad_perm [1,0,3,2]  (xor 1)
    v += dppf<0x4E>(v);    // quad_perm [2,3,0,1]  (xor 2)
    v += dppf<0x141>(v);   // row_half_mirror      (8-group sum)
    v += dppf<0x140>(v);   // row_mirror           (16-group sum)
    return v;              // all 16 lanes of each row hold the 16-sum
}

// ---------------------------------------------------------------------------
// Fused setup: [0,49) map ; [49,145) wpack1 ; [145,721) wconv2 pack ;
// [721,785) stats zero ; [785,2609) h2p halo zero.
// wconv2 pack: w2b holds 18 K-step tiles (t = s*2 + ic_half), each the EXACT
// 16 KB LDS image: [oc 128][8 chunks of 16B], chunk slot = (ic6>>3) ^ (oc&7).
__global__ __launch_bounds__(256) void k_setup(const float* __restrict__ w1,
                                               short* __restrict__ w1b,
                                               const float* __restrict__ w2,
                                               short* __restrict__ w2b,
                                               int2* __restrict__ map,
                                               float* __restrict__ stats,
                                               unsigned* __restrict__ h2p) {
    int blk = blockIdx.x;
    int tid = threadIdx.x;
    if (blk < 49) {
        int p = blk * 256 + tid;
        int oy = p / OUTSZ, ox = p % OUTSZ;
        int e = min(min(oy, ox), min(111 - oy, 111 - ox));
        int s = e >> 3;
        int a = 16 * s, b = a + 16, c = 224 - b, d = 224 - a;
        int ao = a >> 1, bo = b >> 1, co = c >> 1, dd = d >> 1;
        int ti, li, bi, ri;
        if      (oy >= ao && oy < bo && ox >= ao && ox < co) { ti=a; li=a; bi=b; ri=c; }
        else if (oy >= bo && oy < dd && ox >= ao && ox < bo) { ti=b; li=a; bi=d; ri=b; }
        else if (oy >= co && oy < dd && ox >= bo && ox < dd) { ti=c; li=b; bi=d; ri=d; }
        else                                                 { ti=a; li=c; bi=c; ri=d; }
        float scale = (float)(2.0 - (double)s * 0.16666666666666666);
        int tip = (int)((float)(ti + 6) / scale) - 3;
        int lip = (int)((float)(li + 6) / scale) - 3;
        int bip = (int)((float)(bi + 6) / scale) + 3;
        int rip = (int)((float)(ri + 6) / scale) + 3;
        int fh = (bip - tip - 7) / 2 + 1;
        int fw = (rip - lip - 7) / 2 + 1;
        int to = ti >> 1, lo = li >> 1, bo2 = bi >> 1, ro = ri >> 1;
        int i = oy - to, j = ox - lo;
        int pp = (i * fh) / (bo2 - to);
        int qq = (j * fw) / (ro - lo);
        map[p] = make_int2(tip + 2 * pp, lip + 2 * qq);
    } else if (blk < 145) {
        int idx = (blk - 49) * 256 + tid;
        int oc = idx / K1C, k = idx % K1C;
        int g8 = k >> 3, e2 = k & 7;
        float v = 0.f;
        if (g8 < 21 && e2 < 7) {
            int ic = g8 / 7, ky = g8 - ic * 7;
            v = w1[((oc * 3 + ic) * 7 + ky) * 7 + e2];
        }
        w1b[idx] = f2bf(v);
    } else if (blk < 721) {
        int idx = (blk - 145) * 256 + tid;      // input element of w2 (OIHW flat)
        int oc = idx / 1152;
        int rem = idx - oc * 1152;
        int ic = rem / 9;
        int s  = rem - ic * 9;
        int t  = s * 2 + (ic >> 6);             // K-step
        int ic6 = ic & 63;
        int slot = (ic6 >> 3) ^ (oc & 7);       // XOR-swizzled 16B chunk slot
        w2b[t * 8192 + oc * 64 + slot * 8 + (ic6 & 7)] = f2bf(w2[idx]);
    } else if (blk < 785) {
        stats[(blk - 721) * 256 + tid] = 0.f;
    } else {
        int idx = blk - 785;                  // 0..1823
        int bx = idx % 57, n = idx / 57;
        int c2 = tid & 63, po = tid >> 6;
        int pp = bx * 4 + po;                 // 0..227
        int y, x;
        if      (pp < 58)  { y = 0;  x = pp; }
        else if (pp < 116) { y = 57; x = pp - 58; }
        else if (pp < 172) { y = pp - 116 + 1; x = 0; }
        else               { y = pp - 172 + 1; x = 57; }
        h2p[(size_t)n * (HSTRIDE / 2) + (y * HP + x) * 64 + c2] = 0u;
    }
}

// ---------------------------------------------------------------------------
// Zero-haloed padded bf16 input, TWO copies: padA[x] = img[x-3], padB[x] = img[x-2]
__global__ __launch_bounds__(256) void k_pad(const float* __restrict__ inp,
                                             short* __restrict__ padA,
                                             short* __restrict__ padB) {
    int x = threadIdx.x;
    if (x >= PW) return;
    int y = blockIdx.x;       // 0..232
    int pl = blockIdx.y;      // 0..95
    int iy = y - 3;
    bool yok = (unsigned)iy < 224u;
    const float* src = inp + (size_t)pl * 50176 + iy * 224;
    float vA = (yok && (unsigned)(x - 3) < 224u) ? src[x - 3] : 0.f;
    float vB = (yok && (unsigned)(x - 2) < 224u) ? src[x - 2] : 0.f;
    size_t o = (size_t)pl * PPL + y * PW + x;
    padA[o] = f2bf(vA);
    padB[o] = f2bf(vB);
}

// ---------------------------------------------------------------------------
// conv1 v5: wave = 128 oc x 32 px (acc[8][2]); block = 4 waves = 128 px x
// ALL 128 oc. Each pixel's 12x16B im2col gather is now issued ONCE (was twice
// across the two ochalf blocks) -> gather L2 traffic and map reads halve.
// A staged in 51.2 KB LDS: 128 rows x 24 chunks, row pitch 25 chunks (400 B
// == 4-bank shift/row -> 16 rows spread across 8 bank groups, linear slots,
// no XOR VALU). sred aliased into As after a barrier -> LDS = 51.2 KB ->
// 3 blocks/CU (12 waves/CU). XCD n-chunked grid (r4-proven), DPP stats.
__global__ __launch_bounds__(256, 3) void k_conv1m(const short* __restrict__ padA,
                                                   const short* __restrict__ padB,
                                                   const short* __restrict__ w1b,
                                                   const int2* __restrict__ map,
                                                   short* __restrict__ out1b,
                                                   float* __restrict__ sum1x,
                                                   float* __restrict__ sq1x) {
    __shared__ short As[128 * 200];    // 51.2 KB; stats sred aliased in later
    int tid = threadIdx.x;
    int wave = tid >> 6, lane = tid & 63;
    int q = lane >> 4, l16 = lane & 15;
    // XCD-chunked id remap: 3136 = 8 XCD x 392; 392 = 4 images x 98 pxblks.
    int id = blockIdx.x;
    int swz = (id & 7) * 392 + (id >> 3);
    int n = swz / 98;
    int pxblk = swz - n * 98;                         // 0..97
    int px0 = pxblk * 128 + wave * 32 + l16;
    int px1 = px0 + 16;
    int2 m0 = map[px0];
    int2 m1 = map[px1];
    size_t bn = (size_t)n * 3 * PPL;
    const short* r0 = ((m0.y & 1) ? padB + (m0.y - 1) : padA + m0.y) + bn + m0.x * PW;
    const short* r1 = ((m1.y & 1) ? padB + (m1.y - 1) : padA + m1.y) + bn + m1.x * PW;

    // B gathers first (longest latency; consumed in-order by MFMA loop)
    bf16x8 ld[12];
#pragma unroll
    for (int icc = 0; icc < 6; icc++) {
        int g8 = (icc == 5) ? 20 : (icc * 4 + q);
        int ic = (g8 >= 7) + (g8 >= 14);
        int ky = g8 - ic * 7;
        int off = ic * PPL + ky * PW;
        ld[icc * 2]     = ldb8(r0 + off);
        ld[icc * 2 + 1] = ldb8(r1 + off);
    }

    // Stage A: 128 rows x 24 chunks of 16B = 3072 chunks; 12 per thread.
#pragma unroll
    for (int i = 0; i < 12; i++) {
        int chunk = tid + i * 256;
        int r = chunk / 24, c = chunk - r * 24;
        u4a v = *(const u4a*)(w1b + r * K1C + c * 8);
        *(u4a*)(As + r * 200 + c * 8) = v;
    }

    f32x4 acc[8][2];
#pragma unroll
    for (int t = 0; t < 8; t++) { acc[t][0] = (f32x4){0,0,0,0}; acc[t][1] = (f32x4){0,0,0,0}; }

    __syncthreads();

    const short* Abase = As + l16 * 200 + q * 8;   // + t*16*200 + icc*32
#pragma unroll
    for (int icc = 0; icc < 6; icc++) {
        bf16x8 bf0 = ld[icc * 2];
        bf16x8 bf1 = ld[icc * 2 + 1];
#pragma unroll
        for (int t = 0; t < 8; t++) {
            bf16x8 af = *(const bf16x8*)(Abase + t * 3200 + icc * 32);
            acc[t][0] = __builtin_amdgcn_mfma_f32_16x16x32_bf16(af, bf0, acc[t][0], 0, 0, 0);
            acc[t][1] = __builtin_amdgcn_mfma_f32_16x16x32_bf16(af, bf1, acc[t][1], 0, 0, 0);
        }
    }

    // epilogue: C layout col(px)=l16, oc = t*16 + q*4 + r ; store NHWC bf16.
    // 4 q-lanes x 8 t x 8B = full 256 B channel line per px.
    short* ob = out1b + ((size_t)(n * PIX1) + px0) * OCN + q * 4;
#pragma unroll
    for (int t = 0; t < 8; t++) {
#pragma unroll
        for (int g = 0; g < 2; g++) {
            f32x4 a = acc[t][g];
            uint2 u;
            u.x = pack2bf(a[0], a[1]);
            u.y = pack2bf(a[2], a[3]);
            *(uint2*)(ob + (size_t)g * 16 * OCN + t * 16) = u;
        }
    }

    // fused BN1 stats: DPP 16-lane rowsum (VALU only) -> aliased LDS -> combine
    __syncthreads();                    // all As reads done; safe to alias
    float2* sred = (float2*)As;         // [4][128]
#pragma unroll
    for (int t = 0; t < 8; t++) {
#pragma unroll
        for (int r = 0; r < 4; r++) {
            float a0 = acc[t][0][r], a1 = acc[t][1][r];
            float s = rowsum16(a0 + a1);
            float z = rowsum16(fmaf(a0, a0, a1 * a1));
            if (l16 == 0)
                sred[wave * 128 + t * 16 + q * 4 + r] = make_float2(s, z);
        }
    }
    __syncthreads();
    if (tid < 128) {
        float2 p0 = sred[tid], p1 = sred[128 + tid], p2 = sred[256 + tid], p3 = sred[384 + tid];
        float s = p0.x + p1.x + p2.x + p3.x;
        float z = p0.y + p1.y + p2.y + p3.y;
        atomicAdd(&sum1x[n * OCN + tid], s);
        atomicAdd(&sq1x[n * OCN + tid], z);
    }
}

// ---------------------------------------------------------------------------
// Finalize BN params from per-n partial sums: 32x128 -> scale/shift.
__global__ void k_fin2(const float* __restrict__ sumx, const float* __restrict__ sqx,
                       const float* __restrict__ gamma, const float* __restrict__ beta,
                       float invN, float* __restrict__ scale, float* __restrict__ shift) {
    int c = threadIdx.x;
    if (c >= OCN) return;
    float s = 0.f, q = 0.f;
    for (int n = 0; n < BN_; n++) { s += sumx[n * OCN + c]; q += sqx[n * OCN + c]; }
    float m = s * invN;
    float v = q * invN - m * m;
    float sc = gamma[c] * rsqrtf(v + 1e-5f);
    scale[c] = sc;
    shift[c] = beta[c] - m * sc;
}

// ---------------------------------------------------------------------------
// BN1 affine + 3x3/2 maxpool + ReLU: NHWC bf16 (112x112) -> padded NHWC bf16
// (58x58). v5: uint2-vectorized — 32 threads/px, 4 channels/thread, 8 px per
// block. Halves thread count and load-instruction count vs the uint version.
__global__ __launch_bounds__(256) void k_bnpool(const uint2* __restrict__ out1b,
                                                const float* __restrict__ scale,
                                                const float* __restrict__ shift,
                                                uint2* __restrict__ h2p) {
    int tid = threadIdx.x;
    int c4 = tid & 31, po = tid >> 5;
    int pp = blockIdx.x * 8 + po;
    int n = blockIdx.y;
    int py = pp / POOLSZ, px = pp % POOLSZ;
    const uint2* base = out1b + (size_t)n * PIX1 * 32;
    int c0 = c4 * 4;
    float4 sc = *(const float4*)(scale + c0);
    float4 sh = *(const float4*)(shift + c0);
    float m0 = -1e30f, m1 = -1e30f, m2 = -1e30f, m3 = -1e30f;
#pragma unroll
    for (int dy = 0; dy < 3; dy++) {
        int y = 2 * py - 1 + dy;
        if ((unsigned)y >= (unsigned)OUTSZ) continue;
#pragma unroll
        for (int dx = 0; dx < 3; dx++) {
            int x = 2 * px - 1 + dx;
            if ((unsigned)x >= (unsigned)OUTSZ) continue;
            uint2 u = base[(size_t)(y * OUTSZ + x) * 32 + c4];
            m0 = fmaxf(m0, fmaf(sc.x, __uint_as_float(u.x << 16), sh.x));
            m1 = fmaxf(m1, fmaf(sc.y, __uint_as_float(u.x & 0xffff0000u), sh.y));
            m2 = fmaxf(m2, fmaf(sc.z, __uint_as_float(u.y << 16), sh.z));
            m3 = fmaxf(m3, fmaf(sc.w, __uint_as_float(u.y & 0xffff0000u), sh.w));
        }
    }
    uint2 o;
    o.x = pack2bf(fmaxf(m0, 0.f), fmaxf(m1, 0.f));
    o.y = pack2bf(fmaxf(m2, 0.f), fmaxf(m3, 0.f));
    h2p[(size_t)n * (HSTRIDE / 4) + ((py + 1) * HP + (px + 1)) * 32 + c4] = o;
}

// ---------------------------------------------------------------------------
// conv2 v3 (r1-proven, untouched from r4): implicit GEMM, m97 structure.
// M=128 oc, N-tile=112 px (2 rows), BK=64 (18 K-steps). 4 waves, each 32 oc x
// 112 px. A (16 KB) + B (14 KB) single-buffer LDS via global_load_lds w=16;
// 2 barriers/step; 4 blocks/CU. NHWC epilogue; DPP stats.
__global__ __launch_bounds__(256, 4) void k_conv2g(const short* __restrict__ h2p,
                                                   const short* __restrict__ w2b,
                                                   short* __restrict__ out2b,
                                                   float* __restrict__ sum2x,
                                                   float* __restrict__ sq2x) {
    __shared__ short LDSb[15360];          // A: [0,8192) shorts; B: [8192,15360)
    int tid = threadIdx.x;
    int wave = tid >> 6, lane = tid & 63;
    int q = lane >> 4, l16 = lane & 15;
    int id = blockIdx.x;                   // 0..895, XCD-major
    int xcd = id & 7, seq = id >> 3;       // seq 0..111
    int n = xcd + 8 * (seq / 28);
    int rb = seq % 28;
    int y0 = rb * 2;                       // output rows y0, y0+1
    const short* hb = h2p + (size_t)n * HSTRIDE;

    // B staging source offsets (elems, step-delta excluded)
    int bofs[4];
#pragma unroll
    for (int i = 0; i < 4; i++) {
        int ck = tid + i * 256;
        if (ck > 895) ck = 895;            // i==3, tid>=128: lanes inactive
        int px = ck >> 3, sl = ck & 7;
        int r = px >= 56;
        int xc = px - (r ? 56 : 0);
        bofs[i] = ((y0 + r) * 58 + xc) * 128 + ((sl ^ (px & 7)) * 8);
    }

    f32x4 acc[2][7];
#pragma unroll
    for (int t16 = 0; t16 < 2; t16++)
#pragma unroll
        for (int g = 0; g < 7; g++) acc[t16][g] = (f32x4){0, 0, 0, 0};

    const short* Az = LDSb;
    const short* Bz = LDSb + 8192;
    int arow0 = (wave * 32 + l16) * 64;
    int arow1 = arow0 + 16 * 64;

    for (int t = 0; t < 18; t++) {
        __syncthreads();                   // previous compute done in all waves
        // ---- stage A (4x16B/thread, linear) + B (3.5x16B/thread, pre-swz src)
        const short* wt = w2b + t * 8192;
#pragma unroll
        for (int i = 0; i < 4; i++)
            gload16(wt + (tid + i * 256) * 8, &LDSb[(tid + i * 256) * 8]);
        int s = t >> 1, ich = t & 1;
        int dy = s / 3, dx = s - dy * 3;
        int doff = (dy * 58 + dx) * 128 + ich * 64;
#pragma unroll
        for (int i = 0; i < 3; i++)
            gload16(hb + bofs[i] + doff, &LDSb[8192 + (tid + i * 256) * 8]);
        if (tid < 128)
            gload16(hb + bofs[3] + doff, &LDSb[8192 + (tid + 768) * 8]);
        asm volatile("s_waitcnt vmcnt(0)" ::: "memory");
        __syncthreads();
        // ---- compute: 2 k-sub x (2 A-frag reads + 7 B-frag reads + 14 MFMA)
#pragma unroll
        for (int icc2 = 0; icc2 < 2; icc2++) {
            int so = ((icc2 * 4 + q) ^ (l16 & 7)) * 8;
            bf16x8 af0 = *(const bf16x8*)(Az + arow0 + so);
            bf16x8 af1 = *(const bf16x8*)(Az + arow1 + so);
            bf16x8 bf[7];
#pragma unroll
            for (int g = 0; g < 7; g++)
                bf[g] = *(const bf16x8*)(Bz + (g * 16 + l16) * 64 + so);
#pragma unroll
            for (int g = 0; g < 7; g++) {
                acc[0][g] = __builtin_amdgcn_mfma_f32_16x16x32_bf16(af0, bf[g], acc[0][g], 0, 0, 0);
                acc[1][g] = __builtin_amdgcn_mfma_f32_16x16x32_bf16(af1, bf[g], acc[1][g], 0, 0, 0);
            }
        }
    }

    // ---- epilogue: C col(px)=l16, row(oc)=q*4+r ; store NHWC bf16 ----
    short* ob = out2b + ((size_t)n * PIX2 + y0 * 56) * OCN + wave * 32 + q * 4;
#pragma unroll
    for (int t16 = 0; t16 < 2; t16++) {
#pragma unroll
        for (int g = 0; g < 7; g++) {
            f32x4 a = acc[t16][g];
            uint2 u;
            u.x = pack2bf(a[0], a[1]);
            u.y = pack2bf(a[2], a[3]);
            *(uint2*)(ob + (size_t)(g * 16 + l16) * OCN + t16 * 16) = u;
        }
    }

    // ---- fused BN2 stats: DPP rowsum; waves own distinct oc -> atomics ----
#pragma unroll
    for (int t16 = 0; t16 < 2; t16++) {
#pragma unroll
        for (int r = 0; r < 4; r++) {
            float sv = 0.f, zv = 0.f;
#pragma unroll
            for (int g = 0; g < 7; g++) {
                float v = acc[t16][g][r];
                sv += v;
                zv = fmaf(v, v, zv);
            }
            sv = rowsum16(sv);
            zv = rowsum16(zv);
            if (l16 == 0) {
                int oc = wave * 32 + t16 * 16 + q * 4 + r;
                atomicAdd(&sum2x[n * OCN + oc], sv);
                atomicAdd(&sq2x[n * OCN + oc], zv);
            }
        }
    }
}

// ---------------------------------------------------------------------------
// BN2 affine + ReLU: NHWC bf16 out2b -> NCHW fp32 d_out.
// Thread = 4 px x 8 c (x4 c-groups): register-local 4x8 transpose, no LDS.
__global__ __launch_bounds__(256) void k_bnrelu(const short* __restrict__ in2,
                                                float* __restrict__ y,
                                                const float* __restrict__ scale,
                                                const float* __restrict__ shift) {
    int tid = threadIdx.x;
    int w = tid >> 6, l = tid & 63;
    int pxg = blockIdx.x * 256 + w * 64 + (l & 15) * 4;  // wave spans 64 px (never crosses n)
    int n = pxg / PIX2;
    int px = pxg - n * PIX2;
    const short* src = in2 + (size_t)pxg * OCN + (l >> 4) * 8;
    float* dst = y + (size_t)n * (OCN * PIX2) + px;
#pragma unroll
    for (int jc = 0; jc < 4; jc++) {
        int c0 = (l >> 4) * 8 + jc * 32;
        bf16x8 v0 = ldb8(src + jc * 32);
        bf16x8 v1 = ldb8(src + OCN + jc * 32);
        bf16x8 v2 = ldb8(src + 2 * OCN + jc * 32);
        bf16x8 v3 = ldb8(src + 3 * OCN + jc * 32);
#pragma unroll
        for (int j = 0; j < 8; j++) {
            float sc = scale[c0 + j], sh = shift[c0 + j];
            float4 o;
            o.x = fmaxf(fmaf(sc, bf2f(v0[j]), sh), 0.f);
            o.y = fmaxf(fmaf(sc, bf2f(v1[j]), sh), 0.f);
            o.z = fmaxf(fmaf(sc, bf2f(v2[j]), sh), 0.f);
            o.w = fmaxf(fmaf(sc, bf2f(v3[j]), sh), 0.f);
            *(float4*)(dst + (size_t)(c0 + j) * PIX2) = o;
        }
    }
}

// ---------------------------------------------------------------------------
extern "C" void kernel_launch(void* const* d_in, const int* in_sizes, int n_in,
                              void* d_out, int out_size, void* d_ws, size_t ws_size,
                              hipStream_t stream) {
    const float* inp = (const float*)d_in[0];
    const float* w1  = (const float*)d_in[1];
    const float* g1  = (const float*)d_in[2];
    const float* b1  = (const float*)d_in[3];
    const float* w2  = (const float*)d_in[4];
    const float* g2  = (const float*)d_in[5];
    const float* b2  = (const float*)d_in[6];
    float* out = (float*)d_out;

    char* ws = (char*)d_ws;
    int2*  map   = (int2*)ws;                         // 100,352 B
    float* stats = (float*)(ws + 102400);             // 65,536 B zeroed in k_setup
    short* w2b   = (short*)(ws + 176128);             // 294,912 B -> 471,040
    short* w1b   = (short*)(ws + 471040);             // 49,152 B  -> 520,192
    short* padA  = (short*)(ws + 520192);             // 10,736,640 B -> 11,256,832
    short* padB  = (short*)(ws + 11256832ULL);        // 10,736,640 B -> 21,993,472
    short* h2p   = (short*)(ws + 21993472ULL);        // 27,557,888 B -> 49,551,360
    short* out1b = (short*)(ws + 49551360ULL);        // 102,760,448 B -> 152,311,808
    short* out2b = (short*)(ws + 152311808ULL);       // 25,690,112 B -> 178,001,920 (NHWC)

    float* sum1x = stats;                // 32*128
    float* sq1x  = stats + 4096;
    float* sum2x = stats + 8192;
    float* sq2x  = stats + 12288;
    float* SC1 = stats + 16384, *SH1 = stats + 16512;
    float* SC2 = stats + 16640, *SH2 = stats + 16768;

    k_setup <<<dim3(2609), 256, 0, stream>>>(w1, w1b, w2, w2b, map, stats, (unsigned*)h2p);
    k_pad   <<<dim3(PH, 96), 256, 0, stream>>>(inp, padA, padB);
    k_conv1m<<<dim3(3136), 256, 0, stream>>>(padA, padB, w1b, map, out1b, sum1x, sq1x);
    k_fin2  <<<1, 128, 0, stream>>>(sum1x, sq1x, g1, b1, 1.f / (BN_ * PIX1), SC1, SH1);
    k_bnpool<<<dim3(PIX2 / 8, BN_), 256, 0, stream>>>((const uint2*)out1b, SC1, SH1, (uint2*)h2p);
    k_conv2g<<<dim3(896), 256, 0, stream>>>(h2p, w2b, out2b, sum2x, sq2x);
    k_fin2  <<<1, 128, 0, stream>>>(sum2x, sq2x, g2, b2, 1.f / (BN_ * PIX2), SC2, SH2);
    k_bnrelu<<<dim3(392), 256, 0, stream>>>(out2b, out, SC2, SH2);
}